// Round 14
// baseline (343.698 us; speedup 1.0000x reference)
//
#include <hip/hip_runtime.h>
#include <hip/hip_bf16.h>

typedef __hip_bfloat16 bf16;
#define DEV __device__ __forceinline__

constexpr int B_ = 2, C_ = 64, H_ = 96, W_ = 96, L_ = 9216;
constexpr int HD_ = 32, DI_ = 64, N_ = 16, K_ = 4, BB_ = 4;
constexpr int OC_ = 128;
constexpr int CH_ = 768, CL_ = 12;          // scan chunking: 768 chunks of 12 steps
constexpr int SEGN = 16, SEGC = 48;         // scan2: 16 segments x 48 chunks
constexpr float EPSF = 1e-5f;
constexpr int DOWN_SZ = B_ * OC_ * 48 * 48; // 589824

typedef __attribute__((ext_vector_type(8))) short short8;   // 8 bf16 (4 VGPRs)
typedef __attribute__((ext_vector_type(4))) float f32x4;    // MFMA accumulator

DEV float softplusf(float x) { return x > 15.f ? x : __logf(1.f + __expf(x)); }
DEV float b2f(bf16 v) { return __bfloat162float(v); }
DEV float lo16f(unsigned v) { return __uint_as_float(v << 16); }
DEV float hi16f(unsigned v) { return __uint_as_float(v & 0xffff0000u); }
DEV void unpk(uint4 a, uint4 b, float* v) {
  v[0] = lo16f(a.x); v[1] = hi16f(a.x); v[2] = lo16f(a.y); v[3] = hi16f(a.y);
  v[4] = lo16f(a.z); v[5] = hi16f(a.z); v[6] = lo16f(a.w); v[7] = hi16f(a.w);
  v[8] = lo16f(b.x); v[9] = hi16f(b.x); v[10] = lo16f(b.y); v[11] = hi16f(b.y);
  v[12] = lo16f(b.z); v[13] = hi16f(b.z); v[14] = lo16f(b.w); v[15] = hi16f(b.w);
}

// log(1..16): detect A[n] = (n+1)*A[0] structure (VMamba default A_logs)
__constant__ float kLogN[16] = {
  0.0f, 0.69314718f, 1.09861229f, 1.38629436f, 1.60943791f, 1.79175947f,
  1.94591015f, 2.07944154f, 2.19722458f, 2.30258509f, 2.39789527f,
  2.48490665f, 2.56494936f, 2.63905733f, 2.70805020f, 2.77258872f};

// 16 decay powers e1^(n+1) via log-depth binary tree (depth 4, 14 muls)
DEV void pow_tree(float e1, float* ep) {
  float e2 = e1 * e1, e4 = e2 * e2, e8 = e4 * e4;
  float e3 = e2 * e1, e5 = e4 * e1, e6 = e4 * e2, e7 = e4 * e3;
  ep[0] = e1;  ep[1] = e2;  ep[2] = e3;  ep[3] = e4;
  ep[4] = e5;  ep[5] = e6;  ep[6] = e7;  ep[7] = e8;
  ep[8] = e8 * e1;  ep[9] = e8 * e2;  ep[10] = e8 * e3;  ep[11] = e8 * e4;
  ep[12] = e8 * e5; ep[13] = e8 * e6; ep[14] = e8 * e7;  ep[15] = e8 * e8;
}

// loaders (scan-order layout)
DEV void ld_bu(const float* __restrict__ bB, const bf16* __restrict__ ub, int d,
               int ls, int uidx, uint4& qb0, uint4& qb1, float& t0, float& t1, float& u) {
  int uls = __builtin_amdgcn_readfirstlane(ls);
  const float* p = bB + (size_t)uls * 12;
  qb0 = *(const uint4*)p; qb1 = *(const uint4*)(p + 4);
  t0 = p[8]; t1 = p[9];
  u = b2f(ub[(size_t)uidx * DI_ + d]);
}
DEV void ld_bcu(const float* __restrict__ bB, const bf16* __restrict__ bC,
                const bf16* __restrict__ ub, int d, int ls, int uidx,
                uint4& qb0, uint4& qb1, uint4& qc0, uint4& qc1,
                float& t0, float& t1, float& u) {
  int uls = __builtin_amdgcn_readfirstlane(ls);
  const float* p = bB + (size_t)uls * 12;
  qb0 = *(const uint4*)p; qb1 = *(const uint4*)(p + 4);
  t0 = p[8]; t1 = p[9];
  const uint4* cq = (const uint4*)(bC + (size_t)uls * 16);
  qc0 = cq[0]; qc1 = cq[1];
  u = b2f(ub[(size_t)uidx * DI_ + d]);
}

// ---------------- 1: FRONT — wprep + depthwise3x3 + LN(32) + in_proj ----------------
__global__ __launch_bounds__(256, 4) void k_front(
    const float* __restrict__ x, const float* __restrict__ dw33w,
    const float* __restrict__ dw33b, const float* __restrict__ lnw,
    const float* __restrict__ lnb, const float* __restrict__ inw,
    const float* __restrict__ xpw, const float* __restrict__ alog,
    float* __restrict__ xd, float* __restrict__ xzA, bf16* __restrict__ xzBh,
    bf16* __restrict__ wh, float* __restrict__ aux) {
  int bb = blockIdx.y, t = threadIdx.x;
  int b = bb & 1, co = (bb >> 1) * HD_;
  int idx0 = blockIdx.x * 64;
  // one-time prep (blocks y==0): bf16 weight pad + A precompute
  if (bb == 0) {
    int i = blockIdx.x * 256 + t;
    if (i < 144 * 64) {
      int n = i >> 6;
      wh[i] = __float2bfloat16(n < 136 ? xpw[i] : 0.f);
    }
    if (blockIdx.x == 0) {
      int kd = t;  // 256 = K*DI
      const float* al = alog + kd * N_;
      float a0 = al[0];
      bool lin = true;
#pragma unroll
      for (int n = 1; n < N_; n++) lin = lin && (fabsf(al[n] - a0 - kLogN[n]) < 3e-5f);
      aux[kd] = -__expf(a0);
      aux[256 + kd] = lin ? 1.f : 0.f;
#pragma unroll
      for (int n = 0; n < N_; n++) aux[512 + kd * N_ + n] = -__expf(al[n]);
    }
  }
  __shared__ float xds[32 * 68];
  __shared__ float meanA[64], rstdA[64];
  // phase 1: depthwise 3x3 for this (b, 32ch, 64 idx) tile -> LDS + global xd
  for (int i = t; i < 2048; i += 256) {
    int cl = i >> 6, ii = i & 63;
    int sp = idx0 + ii, wi = sp % 96, hi = sp / 96;
    int cg = b * C_ + co + cl;
    float acc = dw33b[co + cl];
#pragma unroll
    for (int dy = -1; dy <= 1; dy++) {
      int hh = hi + dy; if (hh < 0 || hh >= H_) continue;
#pragma unroll
      for (int dx = -1; dx <= 1; dx++) {
        int ww = wi + dx; if (ww < 0 || ww >= W_) continue;
        acc = fmaf(x[(size_t)cg * L_ + sp + dy * 96 + dx],
                   dw33w[(co + cl) * 9 + (dy + 1) * 3 + (dx + 1)], acc);
      }
    }
    xds[cl * 68 + ii] = acc;
    xd[(size_t)cg * L_ + sp] = acc;
  }
  __syncthreads();
  if (t < 64) {
    float s = 0.f, sq = 0.f;
#pragma unroll
    for (int c = 0; c < 32; c++) { float v = xds[c * 68 + t]; s += v; sq = fmaf(v, v, sq); }
    float mean = s * (1.f / HD_);
    float var = sq * (1.f / HD_) - mean * mean;
    meanA[t] = mean; rstdA[t] = rsqrtf(var + EPSF);
  }
  __syncthreads();
  for (int i = t; i < 2048; i += 256) {
    int c = i >> 6, idx = i & 63;
    float v = xds[c * 68 + idx];
    xds[c * 68 + idx] = (v - meanA[idx]) * rstdA[idx] * lnw[c] + lnb[c];
  }
  __syncthreads();
  int oc = t & 127, g = t >> 7;
  float acc[32];
#pragma unroll
  for (int j = 0; j < 32; j++) acc[j] = 0.f;
  for (int c = 0; c < 32; c++) {
    float wv = inw[c * 128 + oc];
    const float4* row = reinterpret_cast<const float4*>(&xds[c * 68 + g * 32]);
#pragma unroll
    for (int j4 = 0; j4 < 8; j4++) {
      float4 xv = row[j4];
      acc[j4 * 4 + 0] = fmaf(xv.x, wv, acc[j4 * 4 + 0]);
      acc[j4 * 4 + 1] = fmaf(xv.y, wv, acc[j4 * 4 + 1]);
      acc[j4 * 4 + 2] = fmaf(xv.z, wv, acc[j4 * 4 + 2]);
      acc[j4 * 4 + 3] = fmaf(xv.w, wv, acc[j4 * 4 + 3]);
    }
  }
  int occ = oc & 63;
  if (oc < 64) {
#pragma unroll
    for (int j = 0; j < 32; j++)
      xzA[(size_t)(bb * L_ + idx0 + g * 32 + j) * 64 + occ] = acc[j];
  } else {
#pragma unroll
    for (int j = 0; j < 32; j++)
      xzBh[(size_t)(bb * L_ + idx0 + g * 32 + j) * 64 + occ] = __float2bfloat16(acc[j]);
  }
}

// ---------------- 2: depthwise 3x3 + SiLU -> xch (spatial) + xcht (transposed) ----------------
__global__ void k_dwsilu(const float* __restrict__ xzA, const float* __restrict__ cw,
                         const float* __restrict__ cb, bf16* __restrict__ xch,
                         bf16* __restrict__ xcht) {
  int t = blockIdx.x * 256 + threadIdx.x;
  int d = t & 63, idx = (t >> 6) % L_, bb = t / (L_ * DI_);
  int wi = idx % W_, hi = idx / W_;
  float acc = cb[d];
#pragma unroll
  for (int dy = -1; dy <= 1; dy++) {
    int hh = hi + dy; if (hh < 0 || hh >= H_) continue;
#pragma unroll
    for (int dx = -1; dx <= 1; dx++) {
      int ww = wi + dx; if (ww < 0 || ww >= W_) continue;
      acc = fmaf(xzA[(size_t)(bb * L_ + hh * W_ + ww) * 64 + d],
                 cw[d * 9 + (dy + 1) * 3 + (dx + 1)], acc);
    }
  }
  acc = acc / (1.f + __expf(-acc));
  bf16 v = __float2bfloat16(acc);
  xch[t] = v;
  int idx_t = wi * 96 + hi;
  xcht[((size_t)bb * L_ + idx_t) * DI_ + d] = v;
}

// ---------------- 3: x_dbl proj via MFMA -> scan-order xdblB / xdblC ----------------
__global__ __launch_bounds__(256, 4) void k_xdbl_mfma(
    const bf16* __restrict__ xch, const bf16* __restrict__ wh,
    float* __restrict__ xdblB, bf16* __restrict__ xdblC) {
  int w = threadIdx.x >> 6, lane = threadIdx.x & 63;
  int bb = blockIdx.y;
  int mtile = blockIdx.x * 4 + w;
  int idx0 = mtile * 16;
  int m = lane & 15, quad = lane >> 4;
  const bf16* arow = xch + ((size_t)bb * L_ + idx0 + m) * 64 + quad * 8;
  short8 a0 = *reinterpret_cast<const short8*>(arow);
  short8 a1 = *reinterpret_cast<const short8*>(arow + 32);
#pragma unroll
  for (int nt = 0; nt < 9; nt++) {
    int n = nt * 16 + m;
    const bf16* brow = wh + n * 64 + quad * 8;
    short8 b0 = *reinterpret_cast<const short8*>(brow);
    short8 b1 = *reinterpret_cast<const short8*>(brow + 32);
    f32x4 acc = {0.f, 0.f, 0.f, 0.f};
    acc = __builtin_amdgcn_mfma_f32_16x16x32_bf16(a0, b0, acc, 0, 0, 0);
    acc = __builtin_amdgcn_mfma_f32_16x16x32_bf16(a1, b1, acc, 0, 0, 0);
    if (n < 136) {
      int k4 = (n >= 102) ? 3 : (n >= 68) ? 2 : (n >= 34) ? 1 : 0;
      int c = n - k4 * 34;
#pragma unroll
      for (int i = 0; i < 4; i++) {
        int r = idx0 + quad * 4 + i;
        int hi2 = r / 96, wi2 = r - hi2 * 96;
        int tr = wi2 * 96 + hi2;
        int ls = (k4 == 0) ? r : (k4 == 1) ? tr : (k4 == 2) ? (L_ - 1 - r) : (L_ - 1 - tr);
        size_t row = (size_t)(bb * K_ + k4) * L_ + ls;
        if (c < 2)       xdblB[row * 12 + 8 + c] = acc[i];
        else if (c < 18) ((bf16*)(xdblB + row * 12))[c - 2] = __float2bfloat16(acc[i]);
        else             xdblC[row * 16 + (c - 18)] = __float2bfloat16(acc[i]);
      }
    }
  }
}

// ---------------- 4: scan1 — per-chunk summaries (h_local, sum dt) ----------------
__global__ __launch_bounds__(256, 4) void k_scan1(
    const float* __restrict__ xdblB, const bf16* __restrict__ xch,
    const bf16* __restrict__ xcht, const float* __restrict__ dtw,
    const float* __restrict__ dtb, const float* __restrict__ aux,
    bf16* __restrict__ hbuf, float* __restrict__ ssum) {
  int w = threadIdx.x >> 6, d = threadIdx.x & 63;
  int chunk = blockIdx.x * 4 + w, k = blockIdx.y, bb = blockIdx.z;
  float w0 = dtw[(k * DI_ + d) * 2 + 0], w1 = dtw[(k * DI_ + d) * 2 + 1];
  float bia = dtb[k * DI_ + d];
  float A1 = aux[k * 64 + d];
  bool chain = (__ballot(aux[256 + k * 64 + d] > 0.5f) == ~0ull);
  float h[N_];
#pragma unroll
  for (int n = 0; n < N_; n++) h[n] = 0.f;
  const float* bB = xdblB + (size_t)(bb * K_ + k) * L_ * 12;
  const bf16* ub = ((k & 1) ? xcht : xch) + (size_t)bb * L_ * DI_;
  int ls0 = chunk * CL_;
  int uidx0 = (k & 2) ? (L_ - 1 - ls0) : ls0;
  int ustep = (k & 2) ? -1 : 1;
  float S = 0.f;
  if (chain) {
#pragma unroll 2
    for (int s = 0; s < CL_; s++) {
      uint4 qb0, qb1; float t0, t1, u;
      ld_bu(bB, ub, d, ls0 + s, uidx0 + s * ustep, qb0, qb1, t0, t1, u);
      float Bv[16];
      unpk(qb0, qb1, Bv);
      float dt = softplusf(fmaf(t0, w0, fmaf(t1, w1, bia)));
      S += dt;
      float du = dt * u;
      float ep[16];
      pow_tree(__expf(dt * A1), ep);
#pragma unroll
      for (int n = 0; n < N_; n++) h[n] = fmaf(ep[n], h[n], du * Bv[n]);
    }
  } else {
    float A[N_];
#pragma unroll
    for (int n = 0; n < N_; n++) A[n] = aux[512 + (k * 64 + d) * N_ + n];
    for (int s = 0; s < CL_; s++) {
      uint4 qb0, qb1; float t0, t1, u;
      ld_bu(bB, ub, d, ls0 + s, uidx0 + s * ustep, qb0, qb1, t0, t1, u);
      float Bv[16];
      unpk(qb0, qb1, Bv);
      float dt = softplusf(fmaf(t0, w0, fmaf(t1, w1, bia)));
      S += dt;
      float du = dt * u;
#pragma unroll
      for (int n = 0; n < N_; n++) h[n] = fmaf(__expf(dt * A[n]), h[n], du * Bv[n]);
    }
  }
  size_t base = (size_t)((bb * K_ + k) * CH_ + chunk) * DI_ + d;
  ssum[base] = S;
#pragma unroll
  for (int n = 0; n < N_; n++) hbuf[base * N_ + n] = __float2bfloat16(h[n]);
}

// ---------------- 5: scan2a — segment-local exclusive scan + raw segment totals ----------------
__global__ __launch_bounds__(256, 4) void k_scan2a(
    const float* __restrict__ aux, const float* __restrict__ ssum,
    bf16* __restrict__ hbuf, float* __restrict__ cumS,
    float* __restrict__ segH, float* __restrict__ segS) {
  int t = blockIdx.x * 256 + threadIdx.x;      // 262144
  int n = t & 15, d = (t >> 4) & 63, kk = (t >> 10) & 3, bb = (t >> 12) & 3, seg = t >> 14;
  float A = aux[512 + (kk * 64 + d) * N_ + n];
  size_t row = (size_t)(bb * K_ + kk) * CH_ * DI_ + d;
  float hp = 0.f, Sc = 0.f;
#pragma unroll 4
  for (int j = 0; j < SEGC; j++) {
    int c = seg * SEGC + j;
    size_t sb = row + (size_t)c * DI_;
    float S = ssum[sb];
    float hl = b2f(hbuf[sb * N_ + n]);
    hbuf[sb * N_ + n] = __float2bfloat16(hp);
    if (n == 0) cumS[sb] = Sc;
    hp = fmaf(__expf(A * S), hp, hl);
    Sc += S;
  }
  size_t sbase = (size_t)(bb * K_ + kk) * SEGN + seg;
  segH[(sbase * DI_ + d) * N_ + n] = hp;       // raw totals (prefix done in scan3)
  if (n == 0) segS[sbase * DI_ + d] = Sc;
}

// ---------------- 6: scan3 — inline segment prefix, replay, y -> ydir ----------------
__global__ __launch_bounds__(256, 4) void k_scan3(
    const float* __restrict__ xdblB, const bf16* __restrict__ xdblC,
    const bf16* __restrict__ xch, const bf16* __restrict__ xcht,
    const float* __restrict__ dtw, const float* __restrict__ dtb,
    const float* __restrict__ Dsw, const float* __restrict__ aux,
    const bf16* __restrict__ hbuf, const float* __restrict__ cumS,
    const float* __restrict__ segH, const float* __restrict__ segS,
    bf16* __restrict__ ydir) {
  int w = threadIdx.x >> 6, d = threadIdx.x & 63;
  int chunk = blockIdx.x * 4 + w, k = blockIdx.y, bb = blockIdx.z;
  float w0 = dtw[(k * DI_ + d) * 2 + 0], w1 = dtw[(k * DI_ + d) * 2 + 1];
  float bia = dtb[k * DI_ + d];
  float Dk = Dsw[k * DI_ + d];
  float A1 = aux[k * 64 + d];
  bool chain = (__ballot(aux[256 + k * 64 + d] > 0.5f) == ~0ull);
  float A[N_];
  if (!chain) {
#pragma unroll
    for (int n = 0; n < N_; n++) A[n] = aux[512 + (k * 64 + d) * N_ + n];
  }
  int seg = chunk / SEGC;
  // segment-initial state = serial prefix over raw segment totals (wave-uniform length)
  float Hi[N_];
#pragma unroll
  for (int n = 0; n < N_; n++) Hi[n] = 0.f;
  for (int s = 0; s < seg; s++) {
    size_t sb = (size_t)(bb * K_ + k) * SEGN + s;
    float Ssg = segS[sb * DI_ + d];
    const float* Hs = segH + (sb * DI_ + d) * N_;
    if (chain) {
      float ep[16];
      pow_tree(__expf(A1 * Ssg), ep);
#pragma unroll
      for (int n = 0; n < N_; n++) Hi[n] = fmaf(ep[n], Hi[n], Hs[n]);
    } else {
#pragma unroll
      for (int n = 0; n < N_; n++) Hi[n] = fmaf(__expf(A[n] * Ssg), Hi[n], Hs[n]);
    }
  }
  float h[N_];
  size_t base = (size_t)((bb * K_ + k) * CH_ + chunk) * DI_ + d;
  float Sc = cumS[base];
  {
    const bf16* hb = hbuf + base * N_;
    uint4 qh0 = *(const uint4*)hb, qh1 = *(const uint4*)(hb + 8);
    unpk(qh0, qh1, h);
    if (chain) {
      float ep[16];
      pow_tree(__expf(A1 * Sc), ep);
#pragma unroll
      for (int n = 0; n < N_; n++) h[n] = fmaf(ep[n], Hi[n], h[n]);
    } else {
#pragma unroll
      for (int n = 0; n < N_; n++) h[n] = fmaf(__expf(A[n] * Sc), Hi[n], h[n]);
    }
  }
  const float* bB = xdblB + (size_t)(bb * K_ + k) * L_ * 12;
  const bf16* bC = xdblC + (size_t)(bb * K_ + k) * L_ * 16;
  const bf16* ub = ((k & 1) ? xcht : xch) + (size_t)bb * L_ * DI_;
  bf16* yb = ydir + (size_t)(bb * K_ + k) * L_ * DI_;
  int ls0 = chunk * CL_;
  int uidx0 = (k & 2) ? (L_ - 1 - ls0) : ls0;
  int ustep = (k & 2) ? -1 : 1;
  if (chain) {
#pragma unroll 2
    for (int s = 0; s < CL_; s++) {
      uint4 qb0, qb1, qc0, qc1; float t0, t1, u;
      ld_bcu(bB, bC, ub, d, ls0 + s, uidx0 + s * ustep, qb0, qb1, qc0, qc1, t0, t1, u);
      float Bv[16], Cv[16];
      unpk(qb0, qb1, Bv); unpk(qc0, qc1, Cv);
      float dt = softplusf(fmaf(t0, w0, fmaf(t1, w1, bia)));
      float du = dt * u;
      float ep[16];
      pow_tree(__expf(dt * A1), ep);
      float m[16];
#pragma unroll
      for (int n = 0; n < N_; n++) {
        h[n] = fmaf(ep[n], h[n], du * Bv[n]);
        m[n] = h[n] * Cv[n];
      }
      float a0 = m[0] + m[1], a1 = m[2] + m[3], a2 = m[4] + m[5], a3 = m[6] + m[7];
      float a4 = m[8] + m[9], a5 = m[10] + m[11], a6 = m[12] + m[13], a7 = m[14] + m[15];
      float b0 = a0 + a1, b1 = a2 + a3, b2 = a4 + a5, b3 = a6 + a7;
      float y = fmaf(Dk, u, (b0 + b1) + (b2 + b3));
      yb[(size_t)(ls0 + s) * DI_ + d] = __float2bfloat16(y);
    }
  } else {
    for (int s = 0; s < CL_; s++) {
      uint4 qb0, qb1, qc0, qc1; float t0, t1, u;
      ld_bcu(bB, bC, ub, d, ls0 + s, uidx0 + s * ustep, qb0, qb1, qc0, qc1, t0, t1, u);
      float Bv[16], Cv[16];
      unpk(qb0, qb1, Bv); unpk(qc0, qc1, Cv);
      float dt = softplusf(fmaf(t0, w0, fmaf(t1, w1, bia)));
      float du = dt * u;
      float y = 0.f;
#pragma unroll
      for (int n = 0; n < N_; n++) {
        h[n] = fmaf(__expf(dt * A[n]), h[n], du * Bv[n]);
        y = fmaf(h[n], Cv[n], y);
      }
      y = fmaf(Dk, u, y);
      yb[(size_t)(ls0 + s) * DI_ + d] = __float2bfloat16(y);
    }
  }
}

// ---------------- 7: sum 4 dirs, LN(64)*silu(z), out_proj, residual -> xm ----------------
__global__ void k_combine(const bf16* __restrict__ ydir, const bf16* __restrict__ xzBh,
                          const float* __restrict__ xd, const float* __restrict__ onw,
                          const float* __restrict__ onb, const float* __restrict__ outw,
                          const float* __restrict__ mssc, float* __restrict__ xm) {
  int w = threadIdx.x >> 6, d = threadIdx.x & 63;
  int idx = blockIdx.x * 4 + w, bb = blockIdx.y;
  int b = bb & 1, co = (bb >> 1) * HD_;
  int hii = idx / 96, wii = idx - hii * 96;
  int lt = wii * 96 + hii;
  const bf16* yd = ydir + (size_t)bb * K_ * L_ * DI_;
  float y = b2f(yd[((size_t)0 * L_ + idx) * DI_ + d])
          + b2f(yd[((size_t)1 * L_ + lt) * DI_ + d])
          + b2f(yd[((size_t)2 * L_ + (L_ - 1 - idx)) * DI_ + d])
          + b2f(yd[((size_t)3 * L_ + (L_ - 1 - lt)) * DI_ + d]);
  float s = y, sq = y * y;
#pragma unroll
  for (int m = 1; m < 64; m <<= 1) { s += __shfl_xor(s, m, 64); sq += __shfl_xor(sq, m, 64); }
  float mean = s * (1.f / DI_);
  float var = sq * (1.f / DI_) - mean * mean;
  float rstd = rsqrtf(var + EPSF);
  float yn = (y - mean) * rstd * onw[d] + onb[d];
  float z = b2f(xzBh[(size_t)(bb * L_ + idx) * 64 + d]);
  float g = yn * (z / (1.f + __expf(-z)));
  __shared__ float gs[4][DI_];
  gs[w][d] = g;
  __syncthreads();
  if (d < HD_) {
    float acc = 0.f;
#pragma unroll
    for (int dd = 0; dd < DI_; dd++) acc = fmaf(gs[w][dd], outw[dd * HD_ + d], acc);
    size_t xi = (size_t)(b * C_ + co + d) * L_ + idx;
    float xp = xd[xi];
    xm[xi] = mssc[0] * xp + xp + acc;
  }
}

// ---------------- 8: fused instance-norm stats (xm) + global mean/max pool (x) ----------------
__global__ __launch_bounds__(1024) void k_stats(
    const float* __restrict__ xm, const float* __restrict__ x,
    float* __restrict__ inm, float* __restrict__ inr,
    float* __restrict__ xmean, float* __restrict__ xmax) {
  int bc = blockIdx.x, t = threadIdx.x;
  const float* pm = xm + (size_t)bc * L_;
  const float* px = x + (size_t)bc * L_;
  float s = 0.f, sq = 0.f, xs = 0.f, mx = -1e30f;
  for (int i = t; i < L_; i += 1024) {
    float v = pm[i]; s += v; sq = fmaf(v, v, sq);
    float xv = px[i]; xs += xv; mx = fmaxf(mx, xv);
  }
  __shared__ float red[64];
#pragma unroll
  for (int m = 1; m < 64; m <<= 1) {
    s += __shfl_xor(s, m, 64); sq += __shfl_xor(sq, m, 64);
    xs += __shfl_xor(xs, m, 64); mx = fmaxf(mx, __shfl_xor(mx, m, 64));
  }
  int wid = t >> 6;
  if ((t & 63) == 0) { red[wid] = s; red[16 + wid] = sq; red[32 + wid] = xs; red[48 + wid] = mx; }
  __syncthreads();
  if (t == 0) {
    s = 0.f; sq = 0.f; xs = 0.f; mx = -1e30f;
#pragma unroll
    for (int i = 0; i < 16; i++) {
      s += red[i]; sq += red[16 + i]; xs += red[32 + i]; mx = fmaxf(mx, red[48 + i]);
    }
    float mean = s * (1.f / L_);
    float var = sq * (1.f / L_) - mean * mean;
    inm[bc] = mean;
    inr[bc] = rsqrtf(var + EPSF);
    xmean[bc] = xs * (1.f / L_);
    xmax[bc] = mx;
  }
}

// ---------------- 9: fused IN+leaky+gate (per tap) + axial convs + BN + relu -> skip ----------------
__global__ void k_axbn(const float* __restrict__ xm, const float* __restrict__ x,
                       const float* __restrict__ inm, const float* __restrict__ inr,
                       const float* __restrict__ msw, const float* __restrict__ msb,
                       const float* __restrict__ xmean, const float* __restrict__ xmax,
                       const float* __restrict__ maw, const float* __restrict__ mab,
                       const float* __restrict__ hw, const float* __restrict__ hb,
                       const float* __restrict__ wwt, const float* __restrict__ wb,
                       const float* __restrict__ bnw, const float* __restrict__ bnb,
                       const float* __restrict__ bnm, const float* __restrict__ bnv,
                       float* __restrict__ skipo) {
  int t = blockIdx.x * 256 + threadIdx.x;
  int bc = t / L_, c = bc & 63, b = bc >> 6;   // uniform per block (256 | L)
  __shared__ float gsh;
  if (threadIdx.x < 64) {
    int ic = threadIdx.x;
    float p = xmean[b * 64 + ic] * maw[(c * 128 + ic) * 9 + 4]
            + xmax[b * 64 + ic] * maw[(c * 128 + 64 + ic) * 9 + 4];
#pragma unroll
    for (int m = 1; m < 64; m <<= 1) p += __shfl_xor(p, m, 64);
    if (ic == 0) gsh = 1.f / (1.f + __expf(-(p + mab[c])));
  }
  __syncthreads();
  float gate = gsh, im = inm[bc], ir = inr[bc], mw = msw[c], mb = msb[c];
  int wi = t % W_, hi = (t / W_) % H_;
  // xs2 value recomputed per tap (same channel -> same gate/IN params)
  auto xsv = [&](int tt) -> float {
    float v = xm[tt];
    v = (v - im) * ir * mw + mb;
    v = v > 0.f ? v : 0.01f * v;
    return v + gate * x[tt];
  };
  float a = xsv(t);
  float hacc = hb[c];
#pragma unroll
  for (int dy = -1; dy <= 1; dy++) {
    int hh = hi + dy; if (hh < 0 || hh >= H_) continue;
    hacc = fmaf(xsv(t + dy * W_), hw[c * 3 + dy + 1], hacc);
  }
  float wacc = wb[c];
#pragma unroll
  for (int dx = -1; dx <= 1; dx++) {
    int ww = wi + dx; if (ww < 0 || ww >= W_) continue;
    wacc = fmaf(xsv(t + dx), wwt[c * 3 + dx + 1], wacc);
  }
  float v = a + hacc + wacc;
  float sv = (v - bnm[c]) * rsqrtf(bnv[c] + EPSF) * bnw[c] + bnb[c];
  skipo[t] = fmaxf(sv, 0.f);
}

// ---------------- 10: 1x1 conv (64->128) + 2x2 maxpool -> down (oc split over z) ----------------
__global__ void k_pwpool(const float* __restrict__ skipo, const float* __restrict__ pww,
                         const float* __restrict__ pwb, float* __restrict__ down) {
  int h2 = blockIdx.x, b = blockIdx.y, t = threadIdx.x;
  int oc0 = blockIdx.z * 32;
  __shared__ float sk[64 * 192];  // [c][r(2)][w(96)]
  for (int i = t; i < 64 * 192; i += 256) {
    int c = i / 192, rw = i % 192, r = rw / 96, wcol = rw % 96;
    sk[i] = skipo[((size_t)(b * C_ + c) * H_ + (2 * h2 + r)) * W_ + wcol];
  }
  __syncthreads();
  for (int o = t; o < 32 * 48; o += 256) {
    int oc = oc0 + o / 48, w2 = o % 48;
    float s0 = 0.f, s1 = 0.f, s2 = 0.f, s3 = 0.f;
#pragma unroll 8
    for (int c = 0; c < 64; c++) {
      float wv = pww[oc * 64 + c];
      const float* sp = &sk[c * 192 + 2 * w2];
      s0 = fmaf(sp[0], wv, s0);
      s1 = fmaf(sp[1], wv, s1);
      s2 = fmaf(sp[96], wv, s2);
      s3 = fmaf(sp[97], wv, s3);
    }
    float v = fmaxf(fmaxf(s0, s1), fmaxf(s2, s3)) + pwb[oc];
    down[((size_t)(b * OC_ + oc) * 48 + h2) * 48 + w2] = v;
  }
}

extern "C" void kernel_launch(void* const* d_in, const int* in_sizes, int n_in,
                              void* d_out, int out_size, void* d_ws, size_t ws_size,
                              hipStream_t stream) {
  const float* x     = (const float*)d_in[0];
  const float* dw33w = (const float*)d_in[1];
  const float* dw33b = (const float*)d_in[2];
  const float* msw   = (const float*)d_in[3];
  const float* msb   = (const float*)d_in[4];
  const float* mssc  = (const float*)d_in[5];
  const float* lnw   = (const float*)d_in[6];
  const float* lnb   = (const float*)d_in[7];
  const float* inw   = (const float*)d_in[8];
  const float* cw    = (const float*)d_in[9];
  const float* cb    = (const float*)d_in[10];
  const float* xpw   = (const float*)d_in[11];
  const float* dtw   = (const float*)d_in[12];
  const float* dtb   = (const float*)d_in[13];
  const float* alog  = (const float*)d_in[14];
  const float* Dsw   = (const float*)d_in[15];
  const float* onw   = (const float*)d_in[16];
  const float* onb   = (const float*)d_in[17];
  const float* outw  = (const float*)d_in[18];
  const float* maw   = (const float*)d_in[19];
  const float* mab   = (const float*)d_in[20];
  const float* ahw   = (const float*)d_in[21];
  const float* ahb   = (const float*)d_in[22];
  const float* aww   = (const float*)d_in[23];
  const float* awb   = (const float*)d_in[24];
  const float* pww   = (const float*)d_in[25];
  const float* pwb   = (const float*)d_in[26];
  const float* bnw   = (const float*)d_in[27];
  const float* bnb   = (const float*)d_in[28];
  const float* bnm   = (const float*)d_in[29];
  const float* bnv   = (const float*)d_in[30];

  float* ws = (float*)d_ws;
  float* xd    = ws;                          // 1,179,648
  float* hreg  = xd + 1179648;                // 6,291,456 slots: hbuf bf16
  bf16*  hbuf  = (bf16*)hreg;
  float* xzA   = hreg;                        // overlays hbuf head (dead before scan1)
  bf16*  xzBh  = (bf16*)(hreg + 6291456);     // 1,179,648 slots
  float* xdblB = hreg + 6291456 + 1179648;    // 147,456 x 12 = 1,769,472
  bf16*  xdblC = (bf16*)(xdblB + 1769472);    // 1,179,648 slots
  float* ssum  = xdblB + 1769472 + 1179648;   // 786,432
  bf16*  ydir  = (bf16*)(ssum + 786432);      // 4,718,592 slots
  float* xmR   = ssum + 786432 + 4718592;     // 1,179,648 (xch early, xm later)
  bf16*  xch   = (bf16*)xmR;
  float* xm    = xmR;
  float* st    = xmR + 1179648;               // 512
  float* inm = st, *inr = st + 128, *xmean = st + 256, *xmaxv = st + 384;
  float* aux   = st + 512;                    // A1(256) + lin(256) + Afull(4096)
  bf16*  wh    = (bf16*)(aux + 4608);         // 9,216 bf16 = 4,608 slots
  float* cumS  = aux + 4608 + 4608;           // 786,432
  float* segH  = cumS + 786432;               // 262,144
  float* segS  = segH + 262144;               // 16,384
  bf16*  xcht  = (bf16*)(segS + 16384);       // 1,179,648 slots

  float* outp = (float*)d_out;
  float* down = outp;
  float* skipo = outp + DOWN_SZ;

  dim3 b256(256);
  int nEl = B_ * C_ * L_;

  k_front<<<dim3(L_ / 64, BB_), b256, 0, stream>>>(x, dw33w, dw33b, lnw, lnb, inw,
                                                   xpw, alog, xd, xzA, xzBh, wh, aux);
  k_dwsilu<<<dim3(BB_ * L_ * DI_ / 256), b256, 0, stream>>>(xzA, cw, cb, xch, xcht);
  k_xdbl_mfma<<<dim3(L_ / 64, BB_), b256, 0, stream>>>(xch, wh, xdblB, xdblC);
  k_scan1<<<dim3(CH_ / 4, K_, BB_), b256, 0, stream>>>(xdblB, xch, xcht, dtw, dtb, aux, hbuf, ssum);
  k_scan2a<<<dim3(BB_ * K_ * SEGN * DI_ * N_ / 256), b256, 0, stream>>>(aux, ssum, hbuf, cumS, segH, segS);
  k_scan3<<<dim3(CH_ / 4, K_, BB_), b256, 0, stream>>>(xdblB, xdblC, xch, xcht, dtw, dtb, Dsw,
                                                      aux, hbuf, cumS, segH, segS, ydir);
  k_combine<<<dim3(L_ / 4, BB_), b256, 0, stream>>>(ydir, xzBh, xd, onw, onb, outw, mssc, xm);
  k_stats<<<dim3(B_ * C_), dim3(1024), 0, stream>>>(xm, x, inm, inr, xmean, xmaxv);
  k_axbn<<<dim3((nEl + 255) / 256), b256, 0, stream>>>(xm, x, inm, inr, msw, msb, xmean, xmaxv,
                                                      maw, mab, ahw, ahb, aww, awb,
                                                      bnw, bnb, bnm, bnv, skipo);
  k_pwpool<<<dim3(48, B_, 4), b256, 0, stream>>>(skipo, pww, pwb, down);
}

// Round 15
// 320.390 us; speedup vs baseline: 1.0727x; 1.0727x over previous
//
#include <hip/hip_runtime.h>
#include <hip/hip_bf16.h>

typedef __hip_bfloat16 bf16;
#define DEV __device__ __forceinline__

constexpr int B_ = 2, C_ = 64, H_ = 96, W_ = 96, L_ = 9216;
constexpr int HD_ = 32, DI_ = 64, N_ = 16, K_ = 4, BB_ = 4;
constexpr int OC_ = 128;
constexpr int CH_ = 768, CL_ = 12;          // scan chunking: 768 chunks of 12 steps
constexpr int SEGN = 16, SEGC = 48;         // scan2: 16 segments x 48 chunks
constexpr float EPSF = 1e-5f;
constexpr int DOWN_SZ = B_ * OC_ * 48 * 48; // 589824

typedef __attribute__((ext_vector_type(8))) short short8;   // 8 bf16 (4 VGPRs)
typedef __attribute__((ext_vector_type(4))) float f32x4;    // MFMA accumulator

DEV float softplusf(float x) { return x > 15.f ? x : __logf(1.f + __expf(x)); }
DEV float b2f(bf16 v) { return __bfloat162float(v); }
DEV float lo16f(unsigned v) { return __uint_as_float(v << 16); }
DEV float hi16f(unsigned v) { return __uint_as_float(v & 0xffff0000u); }
DEV void unpk(uint4 a, uint4 b, float* v) {
  v[0] = lo16f(a.x); v[1] = hi16f(a.x); v[2] = lo16f(a.y); v[3] = hi16f(a.y);
  v[4] = lo16f(a.z); v[5] = hi16f(a.z); v[6] = lo16f(a.w); v[7] = hi16f(a.w);
  v[8] = lo16f(b.x); v[9] = hi16f(b.x); v[10] = lo16f(b.y); v[11] = hi16f(b.y);
  v[12] = lo16f(b.z); v[13] = hi16f(b.z); v[14] = lo16f(b.w); v[15] = hi16f(b.w);
}

// log(1..16): detect A[n] = (n+1)*A[0] structure (VMamba default A_logs)
__constant__ float kLogN[16] = {
  0.0f, 0.69314718f, 1.09861229f, 1.38629436f, 1.60943791f, 1.79175947f,
  1.94591015f, 2.07944154f, 2.19722458f, 2.30258509f, 2.39789527f,
  2.48490665f, 2.56494936f, 2.63905733f, 2.70805020f, 2.77258872f};

// 16 decay powers e1^(n+1) via log-depth binary tree (depth 4, 14 muls)
DEV void pow_tree(float e1, float* ep) {
  float e2 = e1 * e1, e4 = e2 * e2, e8 = e4 * e4;
  float e3 = e2 * e1, e5 = e4 * e1, e6 = e4 * e2, e7 = e4 * e3;
  ep[0] = e1;  ep[1] = e2;  ep[2] = e3;  ep[3] = e4;
  ep[4] = e5;  ep[5] = e6;  ep[6] = e7;  ep[7] = e8;
  ep[8] = e8 * e1;  ep[9] = e8 * e2;  ep[10] = e8 * e3;  ep[11] = e8 * e4;
  ep[12] = e8 * e5; ep[13] = e8 * e6; ep[14] = e8 * e7;  ep[15] = e8 * e8;
}

// loaders (scan-order layout)
DEV void ld_bu(const float* __restrict__ bB, const bf16* __restrict__ ub, int d,
               int ls, int uidx, uint4& qb0, uint4& qb1, float& t0, float& t1, float& u) {
  int uls = __builtin_amdgcn_readfirstlane(ls);
  const float* p = bB + (size_t)uls * 12;
  qb0 = *(const uint4*)p; qb1 = *(const uint4*)(p + 4);
  t0 = p[8]; t1 = p[9];
  u = b2f(ub[(size_t)uidx * DI_ + d]);
}
DEV void ld_bcu(const float* __restrict__ bB, const bf16* __restrict__ bC,
                const bf16* __restrict__ ub, int d, int ls, int uidx,
                uint4& qb0, uint4& qb1, uint4& qc0, uint4& qc1,
                float& t0, float& t1, float& u) {
  int uls = __builtin_amdgcn_readfirstlane(ls);
  const float* p = bB + (size_t)uls * 12;
  qb0 = *(const uint4*)p; qb1 = *(const uint4*)(p + 4);
  t0 = p[8]; t1 = p[9];
  const uint4* cq = (const uint4*)(bC + (size_t)uls * 16);
  qc0 = cq[0]; qc1 = cq[1];
  u = b2f(ub[(size_t)uidx * DI_ + d]);
}

// ---------------- 1: FRONT — wprep + depthwise3x3 + LN(32) + in_proj ----------------
__global__ __launch_bounds__(256, 4) void k_front(
    const float* __restrict__ x, const float* __restrict__ dw33w,
    const float* __restrict__ dw33b, const float* __restrict__ lnw,
    const float* __restrict__ lnb, const float* __restrict__ inw,
    const float* __restrict__ xpw, const float* __restrict__ alog,
    float* __restrict__ xd, float* __restrict__ xzA, bf16* __restrict__ xzBh,
    bf16* __restrict__ wh, float* __restrict__ aux) {
  int bb = blockIdx.y, t = threadIdx.x;
  int b = bb & 1, co = (bb >> 1) * HD_;
  int idx0 = blockIdx.x * 64;
  if (bb == 0) {
    int i = blockIdx.x * 256 + t;
    if (i < 144 * 64) {
      int n = i >> 6;
      wh[i] = __float2bfloat16(n < 136 ? xpw[i] : 0.f);
    }
    if (blockIdx.x == 0) {
      int kd = t;  // 256 = K*DI
      const float* al = alog + kd * N_;
      float a0 = al[0];
      bool lin = true;
#pragma unroll
      for (int n = 1; n < N_; n++) lin = lin && (fabsf(al[n] - a0 - kLogN[n]) < 3e-5f);
      aux[kd] = -__expf(a0);
      aux[256 + kd] = lin ? 1.f : 0.f;
#pragma unroll
      for (int n = 0; n < N_; n++) aux[512 + kd * N_ + n] = -__expf(al[n]);
    }
  }
  __shared__ float xds[32 * 68];
  __shared__ float meanA[64], rstdA[64];
  for (int i = t; i < 2048; i += 256) {
    int cl = i >> 6, ii = i & 63;
    int sp = idx0 + ii, wi = sp % 96, hi = sp / 96;
    int cg = b * C_ + co + cl;
    float acc = dw33b[co + cl];
#pragma unroll
    for (int dy = -1; dy <= 1; dy++) {
      int hh = hi + dy; if (hh < 0 || hh >= H_) continue;
#pragma unroll
      for (int dx = -1; dx <= 1; dx++) {
        int ww = wi + dx; if (ww < 0 || ww >= W_) continue;
        acc = fmaf(x[(size_t)cg * L_ + sp + dy * 96 + dx],
                   dw33w[(co + cl) * 9 + (dy + 1) * 3 + (dx + 1)], acc);
      }
    }
    xds[cl * 68 + ii] = acc;
    xd[(size_t)cg * L_ + sp] = acc;
  }
  __syncthreads();
  if (t < 64) {
    float s = 0.f, sq = 0.f;
#pragma unroll
    for (int c = 0; c < 32; c++) { float v = xds[c * 68 + t]; s += v; sq = fmaf(v, v, sq); }
    float mean = s * (1.f / HD_);
    float var = sq * (1.f / HD_) - mean * mean;
    meanA[t] = mean; rstdA[t] = rsqrtf(var + EPSF);
  }
  __syncthreads();
  for (int i = t; i < 2048; i += 256) {
    int c = i >> 6, idx = i & 63;
    float v = xds[c * 68 + idx];
    xds[c * 68 + idx] = (v - meanA[idx]) * rstdA[idx] * lnw[c] + lnb[c];
  }
  __syncthreads();
  int oc = t & 127, g = t >> 7;
  float acc[32];
#pragma unroll
  for (int j = 0; j < 32; j++) acc[j] = 0.f;
  for (int c = 0; c < 32; c++) {
    float wv = inw[c * 128 + oc];
    const float4* row = reinterpret_cast<const float4*>(&xds[c * 68 + g * 32]);
#pragma unroll
    for (int j4 = 0; j4 < 8; j4++) {
      float4 xv = row[j4];
      acc[j4 * 4 + 0] = fmaf(xv.x, wv, acc[j4 * 4 + 0]);
      acc[j4 * 4 + 1] = fmaf(xv.y, wv, acc[j4 * 4 + 1]);
      acc[j4 * 4 + 2] = fmaf(xv.z, wv, acc[j4 * 4 + 2]);
      acc[j4 * 4 + 3] = fmaf(xv.w, wv, acc[j4 * 4 + 3]);
    }
  }
  int occ = oc & 63;
  if (oc < 64) {
#pragma unroll
    for (int j = 0; j < 32; j++)
      xzA[(size_t)(bb * L_ + idx0 + g * 32 + j) * 64 + occ] = acc[j];
  } else {
#pragma unroll
    for (int j = 0; j < 32; j++)
      xzBh[(size_t)(bb * L_ + idx0 + g * 32 + j) * 64 + occ] = __float2bfloat16(acc[j]);
  }
}

// ---------------- 2: depthwise 3x3 + SiLU -> xch (spatial) + xcht (transposed) ----------------
__global__ void k_dwsilu(const float* __restrict__ xzA, const float* __restrict__ cw,
                         const float* __restrict__ cb, bf16* __restrict__ xch,
                         bf16* __restrict__ xcht) {
  int t = blockIdx.x * 256 + threadIdx.x;
  int d = t & 63, idx = (t >> 6) % L_, bb = t / (L_ * DI_);
  int wi = idx % W_, hi = idx / W_;
  float acc = cb[d];
#pragma unroll
  for (int dy = -1; dy <= 1; dy++) {
    int hh = hi + dy; if (hh < 0 || hh >= H_) continue;
#pragma unroll
    for (int dx = -1; dx <= 1; dx++) {
      int ww = wi + dx; if (ww < 0 || ww >= W_) continue;
      acc = fmaf(xzA[(size_t)(bb * L_ + hh * W_ + ww) * 64 + d],
                 cw[d * 9 + (dy + 1) * 3 + (dx + 1)], acc);
    }
  }
  acc = acc / (1.f + __expf(-acc));
  bf16 v = __float2bfloat16(acc);
  xch[t] = v;
  int idx_t = wi * 96 + hi;
  xcht[((size_t)bb * L_ + idx_t) * DI_ + d] = v;
}

// ---------------- 3: x_dbl proj via MFMA -> scan-order xdblB / xdblC ----------------
__global__ __launch_bounds__(256, 4) void k_xdbl_mfma(
    const bf16* __restrict__ xch, const bf16* __restrict__ wh,
    float* __restrict__ xdblB, bf16* __restrict__ xdblC) {
  int w = threadIdx.x >> 6, lane = threadIdx.x & 63;
  int bb = blockIdx.y;
  int mtile = blockIdx.x * 4 + w;
  int idx0 = mtile * 16;
  int m = lane & 15, quad = lane >> 4;
  const bf16* arow = xch + ((size_t)bb * L_ + idx0 + m) * 64 + quad * 8;
  short8 a0 = *reinterpret_cast<const short8*>(arow);
  short8 a1 = *reinterpret_cast<const short8*>(arow + 32);
#pragma unroll
  for (int nt = 0; nt < 9; nt++) {
    int n = nt * 16 + m;
    const bf16* brow = wh + n * 64 + quad * 8;
    short8 b0 = *reinterpret_cast<const short8*>(brow);
    short8 b1 = *reinterpret_cast<const short8*>(brow + 32);
    f32x4 acc = {0.f, 0.f, 0.f, 0.f};
    acc = __builtin_amdgcn_mfma_f32_16x16x32_bf16(a0, b0, acc, 0, 0, 0);
    acc = __builtin_amdgcn_mfma_f32_16x16x32_bf16(a1, b1, acc, 0, 0, 0);
    if (n < 136) {
      int k4 = (n >= 102) ? 3 : (n >= 68) ? 2 : (n >= 34) ? 1 : 0;
      int c = n - k4 * 34;
#pragma unroll
      for (int i = 0; i < 4; i++) {
        int r = idx0 + quad * 4 + i;
        int hi2 = r / 96, wi2 = r - hi2 * 96;
        int tr = wi2 * 96 + hi2;
        int ls = (k4 == 0) ? r : (k4 == 1) ? tr : (k4 == 2) ? (L_ - 1 - r) : (L_ - 1 - tr);
        size_t row = (size_t)(bb * K_ + k4) * L_ + ls;
        if (c < 2)       xdblB[row * 12 + 8 + c] = acc[i];
        else if (c < 18) ((bf16*)(xdblB + row * 12))[c - 2] = __float2bfloat16(acc[i]);
        else             xdblC[row * 16 + (c - 18)] = __float2bfloat16(acc[i]);
      }
    }
  }
}

// ---------------- 4: scan1 — per-chunk summaries (h_local, sum dt) ----------------
__global__ __launch_bounds__(256, 4) void k_scan1(
    const float* __restrict__ xdblB, const bf16* __restrict__ xch,
    const bf16* __restrict__ xcht, const float* __restrict__ dtw,
    const float* __restrict__ dtb, const float* __restrict__ aux,
    bf16* __restrict__ hbuf, float* __restrict__ ssum) {
  int w = threadIdx.x >> 6, d = threadIdx.x & 63;
  int chunk = blockIdx.x * 4 + w, k = blockIdx.y, bb = blockIdx.z;
  float w0 = dtw[(k * DI_ + d) * 2 + 0], w1 = dtw[(k * DI_ + d) * 2 + 1];
  float bia = dtb[k * DI_ + d];
  float A1 = aux[k * 64 + d];
  bool chain = (__ballot(aux[256 + k * 64 + d] > 0.5f) == ~0ull);
  float h[N_];
#pragma unroll
  for (int n = 0; n < N_; n++) h[n] = 0.f;
  const float* bB = xdblB + (size_t)(bb * K_ + k) * L_ * 12;
  const bf16* ub = ((k & 1) ? xcht : xch) + (size_t)bb * L_ * DI_;
  int ls0 = chunk * CL_;
  int uidx0 = (k & 2) ? (L_ - 1 - ls0) : ls0;
  int ustep = (k & 2) ? -1 : 1;
  float S = 0.f;
  if (chain) {
#pragma unroll 2
    for (int s = 0; s < CL_; s++) {
      uint4 qb0, qb1; float t0, t1, u;
      ld_bu(bB, ub, d, ls0 + s, uidx0 + s * ustep, qb0, qb1, t0, t1, u);
      float Bv[16];
      unpk(qb0, qb1, Bv);
      float dt = softplusf(fmaf(t0, w0, fmaf(t1, w1, bia)));
      S += dt;
      float du = dt * u;
      float ep[16];
      pow_tree(__expf(dt * A1), ep);
#pragma unroll
      for (int n = 0; n < N_; n++) h[n] = fmaf(ep[n], h[n], du * Bv[n]);
    }
  } else {
    float A[N_];
#pragma unroll
    for (int n = 0; n < N_; n++) A[n] = aux[512 + (k * 64 + d) * N_ + n];
    for (int s = 0; s < CL_; s++) {
      uint4 qb0, qb1; float t0, t1, u;
      ld_bu(bB, ub, d, ls0 + s, uidx0 + s * ustep, qb0, qb1, t0, t1, u);
      float Bv[16];
      unpk(qb0, qb1, Bv);
      float dt = softplusf(fmaf(t0, w0, fmaf(t1, w1, bia)));
      S += dt;
      float du = dt * u;
#pragma unroll
      for (int n = 0; n < N_; n++) h[n] = fmaf(__expf(dt * A[n]), h[n], du * Bv[n]);
    }
  }
  size_t base = (size_t)((bb * K_ + k) * CH_ + chunk) * DI_ + d;
  ssum[base] = S;
#pragma unroll
  for (int n = 0; n < N_; n++) hbuf[base * N_ + n] = __float2bfloat16(h[n]);
}

// ---------------- 5: scan2a — segment-local exclusive scan + raw segment totals ----------------
__global__ __launch_bounds__(256, 4) void k_scan2a(
    const float* __restrict__ aux, const float* __restrict__ ssum,
    bf16* __restrict__ hbuf, float* __restrict__ cumS,
    float* __restrict__ segH, float* __restrict__ segS) {
  int t = blockIdx.x * 256 + threadIdx.x;      // 262144
  int n = t & 15, d = (t >> 4) & 63, kk = (t >> 10) & 3, bb = (t >> 12) & 3, seg = t >> 14;
  float A = aux[512 + (kk * 64 + d) * N_ + n];
  size_t row = (size_t)(bb * K_ + kk) * CH_ * DI_ + d;
  float hp = 0.f, Sc = 0.f;
#pragma unroll 4
  for (int j = 0; j < SEGC; j++) {
    int c = seg * SEGC + j;
    size_t sb = row + (size_t)c * DI_;
    float S = ssum[sb];
    float hl = b2f(hbuf[sb * N_ + n]);
    hbuf[sb * N_ + n] = __float2bfloat16(hp);
    if (n == 0) cumS[sb] = Sc;
    hp = fmaf(__expf(A * S), hp, hl);
    Sc += S;
  }
  size_t sbase = (size_t)(bb * K_ + kk) * SEGN + seg;
  segH[(sbase * DI_ + d) * N_ + n] = hp;
  if (n == 0) segS[sbase * DI_ + d] = Sc;
}

// ---------------- 6: scan2b — serial scan over 16 segments (tiny) ----------------
__global__ void k_scan2b(const float* __restrict__ aux, float* __restrict__ segH,
                         const float* __restrict__ segS) {
  int t = blockIdx.x * 256 + threadIdx.x;  // 16384
  int n = t & 15, d = (t >> 4) & 63, kk = (t >> 10) & 3, bb = t >> 12;
  float A = aux[512 + (kk * 64 + d) * N_ + n];
  float hp = 0.f;
  for (int seg = 0; seg < SEGN; seg++) {
    size_t sbase = (size_t)(bb * K_ + kk) * SEGN + seg;
    size_t si = (sbase * DI_ + d) * N_ + n;
    float H = segH[si];
    float E = __expf(A * segS[sbase * DI_ + d]);
    segH[si] = hp;                          // overwrite with segment-initial state
    hp = fmaf(E, hp, H);
  }
}

// ---------------- 7: scan3 — replay with prefixed segH init, y -> ydir ----------------
__global__ __launch_bounds__(256, 4) void k_scan3(
    const float* __restrict__ xdblB, const bf16* __restrict__ xdblC,
    const bf16* __restrict__ xch, const bf16* __restrict__ xcht,
    const float* __restrict__ dtw, const float* __restrict__ dtb,
    const float* __restrict__ Dsw, const float* __restrict__ aux,
    const bf16* __restrict__ hbuf, const float* __restrict__ cumS,
    const float* __restrict__ segH, bf16* __restrict__ ydir) {
  int w = threadIdx.x >> 6, d = threadIdx.x & 63;
  int chunk = blockIdx.x * 4 + w, k = blockIdx.y, bb = blockIdx.z;
  float w0 = dtw[(k * DI_ + d) * 2 + 0], w1 = dtw[(k * DI_ + d) * 2 + 1];
  float bia = dtb[k * DI_ + d];
  float Dk = Dsw[k * DI_ + d];
  float A1 = aux[k * 64 + d];
  bool chain = (__ballot(aux[256 + k * 64 + d] > 0.5f) == ~0ull);
  float h[N_];
  size_t base = (size_t)((bb * K_ + k) * CH_ + chunk) * DI_ + d;
  int seg = chunk / SEGC;
  size_t sbase = (size_t)(bb * K_ + k) * SEGN + seg;
  float Sc = cumS[base];
  {
    const bf16* hb = hbuf + base * N_;
    uint4 qh0 = *(const uint4*)hb, qh1 = *(const uint4*)(hb + 8);
    unpk(qh0, qh1, h);
    const float* Hin = segH + (sbase * DI_ + d) * N_;
    if (chain) {
      float ep[16];
      pow_tree(__expf(A1 * Sc), ep);
#pragma unroll
      for (int n = 0; n < N_; n++) h[n] = fmaf(ep[n], Hin[n], h[n]);
    } else {
#pragma unroll
      for (int n = 0; n < N_; n++) {
        float A = aux[512 + (k * 64 + d) * N_ + n];
        h[n] = fmaf(__expf(A * Sc), Hin[n], h[n]);
      }
    }
  }
  const float* bB = xdblB + (size_t)(bb * K_ + k) * L_ * 12;
  const bf16* bC = xdblC + (size_t)(bb * K_ + k) * L_ * 16;
  const bf16* ub = ((k & 1) ? xcht : xch) + (size_t)bb * L_ * DI_;
  bf16* yb = ydir + (size_t)(bb * K_ + k) * L_ * DI_;
  int ls0 = chunk * CL_;
  int uidx0 = (k & 2) ? (L_ - 1 - ls0) : ls0;
  int ustep = (k & 2) ? -1 : 1;
  if (chain) {
#pragma unroll 2
    for (int s = 0; s < CL_; s++) {
      uint4 qb0, qb1, qc0, qc1; float t0, t1, u;
      ld_bcu(bB, bC, ub, d, ls0 + s, uidx0 + s * ustep, qb0, qb1, qc0, qc1, t0, t1, u);
      float Bv[16], Cv[16];
      unpk(qb0, qb1, Bv); unpk(qc0, qc1, Cv);
      float dt = softplusf(fmaf(t0, w0, fmaf(t1, w1, bia)));
      float du = dt * u;
      float ep[16];
      pow_tree(__expf(dt * A1), ep);
      float m[16];
#pragma unroll
      for (int n = 0; n < N_; n++) {
        h[n] = fmaf(ep[n], h[n], du * Bv[n]);
        m[n] = h[n] * Cv[n];
      }
      float a0 = m[0] + m[1], a1 = m[2] + m[3], a2 = m[4] + m[5], a3 = m[6] + m[7];
      float a4 = m[8] + m[9], a5 = m[10] + m[11], a6 = m[12] + m[13], a7 = m[14] + m[15];
      float b0 = a0 + a1, b1 = a2 + a3, b2 = a4 + a5, b3 = a6 + a7;
      float y = fmaf(Dk, u, (b0 + b1) + (b2 + b3));
      yb[(size_t)(ls0 + s) * DI_ + d] = __float2bfloat16(y);
    }
  } else {
    float A[N_];
#pragma unroll
    for (int n = 0; n < N_; n++) A[n] = aux[512 + (k * 64 + d) * N_ + n];
    for (int s = 0; s < CL_; s++) {
      uint4 qb0, qb1, qc0, qc1; float t0, t1, u;
      ld_bcu(bB, bC, ub, d, ls0 + s, uidx0 + s * ustep, qb0, qb1, qc0, qc1, t0, t1, u);
      float Bv[16], Cv[16];
      unpk(qb0, qb1, Bv); unpk(qc0, qc1, Cv);
      float dt = softplusf(fmaf(t0, w0, fmaf(t1, w1, bia)));
      float du = dt * u;
      float y = 0.f;
#pragma unroll
      for (int n = 0; n < N_; n++) {
        h[n] = fmaf(__expf(dt * A[n]), h[n], du * Bv[n]);
        y = fmaf(h[n], Cv[n], y);
      }
      y = fmaf(Dk, u, y);
      yb[(size_t)(ls0 + s) * DI_ + d] = __float2bfloat16(y);
    }
  }
}

// ---------------- 8: sum 4 dirs, LN(64)*silu(z), out_proj, residual -> xm ----------------
__global__ void k_combine(const bf16* __restrict__ ydir, const bf16* __restrict__ xzBh,
                          const float* __restrict__ xd, const float* __restrict__ onw,
                          const float* __restrict__ onb, const float* __restrict__ outw,
                          const float* __restrict__ mssc, float* __restrict__ xm) {
  int w = threadIdx.x >> 6, d = threadIdx.x & 63;
  int idx = blockIdx.x * 4 + w, bb = blockIdx.y;
  int b = bb & 1, co = (bb >> 1) * HD_;
  int hii = idx / 96, wii = idx - hii * 96;
  int lt = wii * 96 + hii;
  const bf16* yd = ydir + (size_t)bb * K_ * L_ * DI_;
  float y = b2f(yd[((size_t)0 * L_ + idx) * DI_ + d])
          + b2f(yd[((size_t)1 * L_ + lt) * DI_ + d])
          + b2f(yd[((size_t)2 * L_ + (L_ - 1 - idx)) * DI_ + d])
          + b2f(yd[((size_t)3 * L_ + (L_ - 1 - lt)) * DI_ + d]);
  float s = y, sq = y * y;
#pragma unroll
  for (int m = 1; m < 64; m <<= 1) { s += __shfl_xor(s, m, 64); sq += __shfl_xor(sq, m, 64); }
  float mean = s * (1.f / DI_);
  float var = sq * (1.f / DI_) - mean * mean;
  float rstd = rsqrtf(var + EPSF);
  float yn = (y - mean) * rstd * onw[d] + onb[d];
  float z = b2f(xzBh[(size_t)(bb * L_ + idx) * 64 + d]);
  float g = yn * (z / (1.f + __expf(-z)));
  __shared__ float gs[4][DI_];
  gs[w][d] = g;
  __syncthreads();
  if (d < HD_) {
    float acc = 0.f;
#pragma unroll
    for (int dd = 0; dd < DI_; dd++) acc = fmaf(gs[w][dd], outw[dd * HD_ + d], acc);
    size_t xi = (size_t)(b * C_ + co + d) * L_ + idx;
    float xp = xd[xi];
    xm[xi] = mssc[0] * xp + xp + acc;
  }
}

// ---------------- 9: fused instance-norm stats (xm) + global mean/max pool (x) ----------------
__global__ __launch_bounds__(1024) void k_stats(
    const float* __restrict__ xm, const float* __restrict__ x,
    float* __restrict__ inm, float* __restrict__ inr,
    float* __restrict__ xmean, float* __restrict__ xmax) {
  int bc = blockIdx.x, t = threadIdx.x;
  const float* pm = xm + (size_t)bc * L_;
  const float* px = x + (size_t)bc * L_;
  float s = 0.f, sq = 0.f, xs = 0.f, mx = -1e30f;
  for (int i = t; i < L_; i += 1024) {
    float v = pm[i]; s += v; sq = fmaf(v, v, sq);
    float xv = px[i]; xs += xv; mx = fmaxf(mx, xv);
  }
  __shared__ float red[64];
#pragma unroll
  for (int m = 1; m < 64; m <<= 1) {
    s += __shfl_xor(s, m, 64); sq += __shfl_xor(sq, m, 64);
    xs += __shfl_xor(xs, m, 64); mx = fmaxf(mx, __shfl_xor(mx, m, 64));
  }
  int wid = t >> 6;
  if ((t & 63) == 0) { red[wid] = s; red[16 + wid] = sq; red[32 + wid] = xs; red[48 + wid] = mx; }
  __syncthreads();
  if (t == 0) {
    s = 0.f; sq = 0.f; xs = 0.f; mx = -1e30f;
#pragma unroll
    for (int i = 0; i < 16; i++) {
      s += red[i]; sq += red[16 + i]; xs += red[32 + i]; mx = fmaxf(mx, red[48 + i]);
    }
    float mean = s * (1.f / L_);
    float var = sq * (1.f / L_) - mean * mean;
    inm[bc] = mean;
    inr[bc] = rsqrtf(var + EPSF);
    xmean[bc] = xs * (1.f / L_);
    xmax[bc] = mx;
  }
}

// ---------------- 10: fused IN+leaky+gate (per tap) + axial convs + BN + relu -> skip ----------------
__global__ void k_axbn(const float* __restrict__ xm, const float* __restrict__ x,
                       const float* __restrict__ inm, const float* __restrict__ inr,
                       const float* __restrict__ msw, const float* __restrict__ msb,
                       const float* __restrict__ xmean, const float* __restrict__ xmax,
                       const float* __restrict__ maw, const float* __restrict__ mab,
                       const float* __restrict__ hw, const float* __restrict__ hb,
                       const float* __restrict__ wwt, const float* __restrict__ wb,
                       const float* __restrict__ bnw, const float* __restrict__ bnb,
                       const float* __restrict__ bnm, const float* __restrict__ bnv,
                       float* __restrict__ skipo) {
  int t = blockIdx.x * 256 + threadIdx.x;
  int bc = t / L_, c = bc & 63, b = bc >> 6;   // uniform per block (256 | L)
  __shared__ float gsh;
  if (threadIdx.x < 64) {
    int ic = threadIdx.x;
    float p = xmean[b * 64 + ic] * maw[(c * 128 + ic) * 9 + 4]
            + xmax[b * 64 + ic] * maw[(c * 128 + 64 + ic) * 9 + 4];
#pragma unroll
    for (int m = 1; m < 64; m <<= 1) p += __shfl_xor(p, m, 64);
    if (ic == 0) gsh = 1.f / (1.f + __expf(-(p + mab[c])));
  }
  __syncthreads();
  float gate = gsh, im = inm[bc], ir = inr[bc], mw = msw[c], mb = msb[c];
  int wi = t % W_, hi = (t / W_) % H_;
  auto xsv = [&](int tt) -> float {
    float v = xm[tt];
    v = (v - im) * ir * mw + mb;
    v = v > 0.f ? v : 0.01f * v;
    return v + gate * x[tt];
  };
  float a = xsv(t);
  float hacc = hb[c];
#pragma unroll
  for (int dy = -1; dy <= 1; dy++) {
    int hh = hi + dy; if (hh < 0 || hh >= H_) continue;
    hacc = fmaf(xsv(t + dy * W_), hw[c * 3 + dy + 1], hacc);
  }
  float wacc = wb[c];
#pragma unroll
  for (int dx = -1; dx <= 1; dx++) {
    int ww = wi + dx; if (ww < 0 || ww >= W_) continue;
    wacc = fmaf(xsv(t + dx), wwt[c * 3 + dx + 1], wacc);
  }
  float v = a + hacc + wacc;
  float sv = (v - bnm[c]) * rsqrtf(bnv[c] + EPSF) * bnw[c] + bnb[c];
  skipo[t] = fmaxf(sv, 0.f);
}

// ---------------- 11: 1x1 conv (64->128) + 2x2 maxpool -> down (oc split over z) ----------------
__global__ void k_pwpool(const float* __restrict__ skipo, const float* __restrict__ pww,
                         const float* __restrict__ pwb, float* __restrict__ down) {
  int h2 = blockIdx.x, b = blockIdx.y, t = threadIdx.x;
  int oc0 = blockIdx.z * 32;
  __shared__ float sk[64 * 192];  // [c][r(2)][w(96)]
  for (int i = t; i < 64 * 192; i += 256) {
    int c = i / 192, rw = i % 192, r = rw / 96, wcol = rw % 96;
    sk[i] = skipo[((size_t)(b * C_ + c) * H_ + (2 * h2 + r)) * W_ + wcol];
  }
  __syncthreads();
  for (int o = t; o < 32 * 48; o += 256) {
    int oc = oc0 + o / 48, w2 = o % 48;
    float s0 = 0.f, s1 = 0.f, s2 = 0.f, s3 = 0.f;
#pragma unroll 8
    for (int c = 0; c < 64; c++) {
      float wv = pww[oc * 64 + c];
      const float* sp = &sk[c * 192 + 2 * w2];
      s0 = fmaf(sp[0], wv, s0);
      s1 = fmaf(sp[1], wv, s1);
      s2 = fmaf(sp[96], wv, s2);
      s3 = fmaf(sp[97], wv, s3);
    }
    float v = fmaxf(fmaxf(s0, s1), fmaxf(s2, s3)) + pwb[oc];
    down[((size_t)(b * OC_ + oc) * 48 + h2) * 48 + w2] = v;
  }
}

extern "C" void kernel_launch(void* const* d_in, const int* in_sizes, int n_in,
                              void* d_out, int out_size, void* d_ws, size_t ws_size,
                              hipStream_t stream) {
  const float* x     = (const float*)d_in[0];
  const float* dw33w = (const float*)d_in[1];
  const float* dw33b = (const float*)d_in[2];
  const float* msw   = (const float*)d_in[3];
  const float* msb   = (const float*)d_in[4];
  const float* mssc  = (const float*)d_in[5];
  const float* lnw   = (const float*)d_in[6];
  const float* lnb   = (const float*)d_in[7];
  const float* inw   = (const float*)d_in[8];
  const float* cw    = (const float*)d_in[9];
  const float* cb    = (const float*)d_in[10];
  const float* xpw   = (const float*)d_in[11];
  const float* dtw   = (const float*)d_in[12];
  const float* dtb   = (const float*)d_in[13];
  const float* alog  = (const float*)d_in[14];
  const float* Dsw   = (const float*)d_in[15];
  const float* onw   = (const float*)d_in[16];
  const float* onb   = (const float*)d_in[17];
  const float* outw  = (const float*)d_in[18];
  const float* maw   = (const float*)d_in[19];
  const float* mab   = (const float*)d_in[20];
  const float* ahw   = (const float*)d_in[21];
  const float* ahb   = (const float*)d_in[22];
  const float* aww   = (const float*)d_in[23];
  const float* awb   = (const float*)d_in[24];
  const float* pww   = (const float*)d_in[25];
  const float* pwb   = (const float*)d_in[26];
  const float* bnw   = (const float*)d_in[27];
  const float* bnb   = (const float*)d_in[28];
  const float* bnm   = (const float*)d_in[29];
  const float* bnv   = (const float*)d_in[30];

  float* ws = (float*)d_ws;
  float* xd    = ws;                          // 1,179,648
  float* hreg  = xd + 1179648;                // 6,291,456 slots: hbuf bf16
  bf16*  hbuf  = (bf16*)hreg;
  float* xzA   = hreg;                        // overlays hbuf head (dead before scan1)
  bf16*  xzBh  = (bf16*)(hreg + 6291456);     // 1,179,648 slots
  float* xdblB = hreg + 6291456 + 1179648;    // 147,456 x 12 = 1,769,472
  bf16*  xdblC = (bf16*)(xdblB + 1769472);    // 1,179,648 slots
  float* ssum  = xdblB + 1769472 + 1179648;   // 786,432
  bf16*  ydir  = (bf16*)(ssum + 786432);      // 4,718,592 slots
  float* xmR   = ssum + 786432 + 4718592;     // 1,179,648 (xch early, xm later)
  bf16*  xch   = (bf16*)xmR;
  float* xm    = xmR;
  float* st    = xmR + 1179648;               // 512
  float* inm = st, *inr = st + 128, *xmean = st + 256, *xmaxv = st + 384;
  float* aux   = st + 512;                    // A1(256) + lin(256) + Afull(4096)
  bf16*  wh    = (bf16*)(aux + 4608);         // 9,216 bf16 = 4,608 slots
  float* cumS  = aux + 4608 + 4608;           // 786,432
  float* segH  = cumS + 786432;               // 262,144
  float* segS  = segH + 262144;               // 16,384
  bf16*  xcht  = (bf16*)(segS + 16384);       // 1,179,648 slots

  float* outp = (float*)d_out;
  float* down = outp;
  float* skipo = outp + DOWN_SZ;

  dim3 b256(256);
  int nEl = B_ * C_ * L_;

  k_front<<<dim3(L_ / 64, BB_), b256, 0, stream>>>(x, dw33w, dw33b, lnw, lnb, inw,
                                                   xpw, alog, xd, xzA, xzBh, wh, aux);
  k_dwsilu<<<dim3(BB_ * L_ * DI_ / 256), b256, 0, stream>>>(xzA, cw, cb, xch, xcht);
  k_xdbl_mfma<<<dim3(L_ / 64, BB_), b256, 0, stream>>>(xch, wh, xdblB, xdblC);
  k_scan1<<<dim3(CH_ / 4, K_, BB_), b256, 0, stream>>>(xdblB, xch, xcht, dtw, dtb, aux, hbuf, ssum);
  k_scan2a<<<dim3(BB_ * K_ * SEGN * DI_ * N_ / 256), b256, 0, stream>>>(aux, ssum, hbuf, cumS, segH, segS);
  k_scan2b<<<dim3(BB_ * K_ * DI_ * N_ / 256), b256, 0, stream>>>(aux, segH, segS);
  k_scan3<<<dim3(CH_ / 4, K_, BB_), b256, 0, stream>>>(xdblB, xdblC, xch, xcht, dtw, dtb, Dsw,
                                                      aux, hbuf, cumS, segH, ydir);
  k_combine<<<dim3(L_ / 4, BB_), b256, 0, stream>>>(ydir, xzBh, xd, onw, onb, outw, mssc, xm);
  k_stats<<<dim3(B_ * C_), dim3(1024), 0, stream>>>(xm, x, inm, inr, xmean, xmaxv);
  k_axbn<<<dim3((nEl + 255) / 256), b256, 0, stream>>>(xm, x, inm, inr, msw, msb, xmean, xmaxv,
                                                      maw, mab, ahw, ahb, aww, awb,
                                                      bnw, bnb, bnm, bnv, skipo);
  k_pwpool<<<dim3(48, B_, 4), b256, 0, stream>>>(skipo, pww, pwb, down);
}

// Round 16
// 311.527 us; speedup vs baseline: 1.1033x; 1.0285x over previous
//
#include <hip/hip_runtime.h>
#include <hip/hip_bf16.h>

typedef __hip_bfloat16 bf16;
#define DEV __device__ __forceinline__

constexpr int B_ = 2, C_ = 64, H_ = 96, W_ = 96, L_ = 9216;
constexpr int HD_ = 32, DI_ = 64, N_ = 16, K_ = 4, BB_ = 4;
constexpr int OC_ = 128;
constexpr int CH_ = 1536, CL_ = 6;          // scan chunking: 1536 chunks of 6 steps
constexpr int SEGN = 32, SEGC = 48;         // scan2: 32 segments x 48 chunks
constexpr float EPSF = 1e-5f;
constexpr int DOWN_SZ = B_ * OC_ * 48 * 48; // 589824

typedef __attribute__((ext_vector_type(8))) short short8;   // 8 bf16 (4 VGPRs)
typedef __attribute__((ext_vector_type(4))) float f32x4;    // MFMA accumulator

DEV float softplusf(float x) { return x > 15.f ? x : __logf(1.f + __expf(x)); }
DEV float b2f(bf16 v) { return __bfloat162float(v); }
DEV float lo16f(unsigned v) { return __uint_as_float(v << 16); }
DEV float hi16f(unsigned v) { return __uint_as_float(v & 0xffff0000u); }
DEV void unpk(uint4 a, uint4 b, float* v) {
  v[0] = lo16f(a.x); v[1] = hi16f(a.x); v[2] = lo16f(a.y); v[3] = hi16f(a.y);
  v[4] = lo16f(a.z); v[5] = hi16f(a.z); v[6] = lo16f(a.w); v[7] = hi16f(a.w);
  v[8] = lo16f(b.x); v[9] = hi16f(b.x); v[10] = lo16f(b.y); v[11] = hi16f(b.y);
  v[12] = lo16f(b.z); v[13] = hi16f(b.z); v[14] = lo16f(b.w); v[15] = hi16f(b.w);
}

// log(1..16): detect A[n] = (n+1)*A[0] structure (VMamba default A_logs)
__constant__ float kLogN[16] = {
  0.0f, 0.69314718f, 1.09861229f, 1.38629436f, 1.60943791f, 1.79175947f,
  1.94591015f, 2.07944154f, 2.19722458f, 2.30258509f, 2.39789527f,
  2.48490665f, 2.56494936f, 2.63905733f, 2.70805020f, 2.77258872f};

// 16 decay powers e1^(n+1) via log-depth binary tree (depth 4, 14 muls)
DEV void pow_tree(float e1, float* ep) {
  float e2 = e1 * e1, e4 = e2 * e2, e8 = e4 * e4;
  float e3 = e2 * e1, e5 = e4 * e1, e6 = e4 * e2, e7 = e4 * e3;
  ep[0] = e1;  ep[1] = e2;  ep[2] = e3;  ep[3] = e4;
  ep[4] = e5;  ep[5] = e6;  ep[6] = e7;  ep[7] = e8;
  ep[8] = e8 * e1;  ep[9] = e8 * e2;  ep[10] = e8 * e3;  ep[11] = e8 * e4;
  ep[12] = e8 * e5; ep[13] = e8 * e6; ep[14] = e8 * e7;  ep[15] = e8 * e8;
}

// loaders (scan-order layout)
DEV void ld_bu(const float* __restrict__ bB, const bf16* __restrict__ ub, int d,
               int ls, int uidx, uint4& qb0, uint4& qb1, float& t0, float& t1, float& u) {
  int uls = __builtin_amdgcn_readfirstlane(ls);
  const float* p = bB + (size_t)uls * 12;
  qb0 = *(const uint4*)p; qb1 = *(const uint4*)(p + 4);
  t0 = p[8]; t1 = p[9];
  u = b2f(ub[(size_t)uidx * DI_ + d]);
}
DEV void ld_bcu(const float* __restrict__ bB, const bf16* __restrict__ bC,
                const bf16* __restrict__ ub, int d, int ls, int uidx,
                uint4& qb0, uint4& qb1, uint4& qc0, uint4& qc1,
                float& t0, float& t1, float& u) {
  int uls = __builtin_amdgcn_readfirstlane(ls);
  const float* p = bB + (size_t)uls * 12;
  qb0 = *(const uint4*)p; qb1 = *(const uint4*)(p + 4);
  t0 = p[8]; t1 = p[9];
  const uint4* cq = (const uint4*)(bC + (size_t)uls * 16);
  qc0 = cq[0]; qc1 = cq[1];
  u = b2f(ub[(size_t)uidx * DI_ + d]);
}

// ---------------- 1: FRONT — wprep + depthwise3x3 + LN(32) + in_proj (32-idx tiles) ----------------
__global__ __launch_bounds__(256, 4) void k_front(
    const float* __restrict__ x, const float* __restrict__ dw33w,
    const float* __restrict__ dw33b, const float* __restrict__ lnw,
    const float* __restrict__ lnb, const float* __restrict__ inw,
    const float* __restrict__ xpw, const float* __restrict__ alog,
    float* __restrict__ xd, bf16* __restrict__ xzAh, bf16* __restrict__ xzBh,
    bf16* __restrict__ wh, float* __restrict__ aux) {
  int bb = blockIdx.y, t = threadIdx.x;
  int b = bb & 1, co = (bb >> 1) * HD_;
  int idx0 = blockIdx.x * 32;
  if (bb == 0) {
    int i = blockIdx.x * 256 + t;
    if (i < 144 * 64) {
      int n = i >> 6;
      wh[i] = __float2bfloat16(n < 136 ? xpw[i] : 0.f);
    }
    if (blockIdx.x == 0) {
      int kd = t;  // 256 = K*DI
      const float* al = alog + kd * N_;
      float a0 = al[0];
      bool lin = true;
#pragma unroll
      for (int n = 1; n < N_; n++) lin = lin && (fabsf(al[n] - a0 - kLogN[n]) < 3e-5f);
      aux[kd] = -__expf(a0);
      aux[256 + kd] = lin ? 1.f : 0.f;
#pragma unroll
      for (int n = 0; n < N_; n++) aux[512 + kd * N_ + n] = -__expf(al[n]);
    }
  }
  __shared__ float xds[32 * 36];
  __shared__ float meanA[32], rstdA[32];
  for (int i = t; i < 1024; i += 256) {
    int cl = i >> 5, ii = i & 31;
    int sp = idx0 + ii, wi = sp % 96, hi = sp / 96;
    int cg = b * C_ + co + cl;
    float acc = dw33b[co + cl];
#pragma unroll
    for (int dy = -1; dy <= 1; dy++) {
      int hh = hi + dy; if (hh < 0 || hh >= H_) continue;
#pragma unroll
      for (int dx = -1; dx <= 1; dx++) {
        int ww = wi + dx; if (ww < 0 || ww >= W_) continue;
        acc = fmaf(x[(size_t)cg * L_ + sp + dy * 96 + dx],
                   dw33w[(co + cl) * 9 + (dy + 1) * 3 + (dx + 1)], acc);
      }
    }
    xds[cl * 36 + ii] = acc;
    xd[(size_t)cg * L_ + sp] = acc;
  }
  __syncthreads();
  if (t < 32) {
    float s = 0.f, sq = 0.f;
#pragma unroll
    for (int c = 0; c < 32; c++) { float v = xds[c * 36 + t]; s += v; sq = fmaf(v, v, sq); }
    float mean = s * (1.f / HD_);
    float var = sq * (1.f / HD_) - mean * mean;
    meanA[t] = mean; rstdA[t] = rsqrtf(var + EPSF);
  }
  __syncthreads();
  for (int i = t; i < 1024; i += 256) {
    int c = i >> 5, idx = i & 31;
    float v = xds[c * 36 + idx];
    xds[c * 36 + idx] = (v - meanA[idx]) * rstdA[idx] * lnw[c] + lnb[c];
  }
  __syncthreads();
  int oc = t & 127, g = t >> 7;
  float acc[16];
#pragma unroll
  for (int j = 0; j < 16; j++) acc[j] = 0.f;
  for (int c = 0; c < 32; c++) {
    float wv = inw[c * 128 + oc];
    const float4* row = reinterpret_cast<const float4*>(&xds[c * 36 + g * 16]);
#pragma unroll
    for (int j4 = 0; j4 < 4; j4++) {
      float4 xv = row[j4];
      acc[j4 * 4 + 0] = fmaf(xv.x, wv, acc[j4 * 4 + 0]);
      acc[j4 * 4 + 1] = fmaf(xv.y, wv, acc[j4 * 4 + 1]);
      acc[j4 * 4 + 2] = fmaf(xv.z, wv, acc[j4 * 4 + 2]);
      acc[j4 * 4 + 3] = fmaf(xv.w, wv, acc[j4 * 4 + 3]);
    }
  }
  int occ = oc & 63;
  if (oc < 64) {
#pragma unroll
    for (int j = 0; j < 16; j++)
      xzAh[(size_t)(bb * L_ + idx0 + g * 16 + j) * 64 + occ] = __float2bfloat16(acc[j]);
  } else {
#pragma unroll
    for (int j = 0; j < 16; j++)
      xzBh[(size_t)(bb * L_ + idx0 + g * 16 + j) * 64 + occ] = __float2bfloat16(acc[j]);
  }
}

// ---------------- 2: depthwise 3x3 + SiLU -> xch (spatial) + xcht (transposed) ----------------
__global__ void k_dwsilu(const bf16* __restrict__ xzAh, const float* __restrict__ cw,
                         const float* __restrict__ cb, bf16* __restrict__ xch,
                         bf16* __restrict__ xcht) {
  int t = blockIdx.x * 256 + threadIdx.x;
  int d = t & 63, idx = (t >> 6) % L_, bb = t / (L_ * DI_);
  int wi = idx % W_, hi = idx / W_;
  float acc = cb[d];
#pragma unroll
  for (int dy = -1; dy <= 1; dy++) {
    int hh = hi + dy; if (hh < 0 || hh >= H_) continue;
#pragma unroll
    for (int dx = -1; dx <= 1; dx++) {
      int ww = wi + dx; if (ww < 0 || ww >= W_) continue;
      acc = fmaf(b2f(xzAh[(size_t)(bb * L_ + hh * W_ + ww) * 64 + d]),
                 cw[d * 9 + (dy + 1) * 3 + (dx + 1)], acc);
    }
  }
  acc = acc / (1.f + __expf(-acc));
  bf16 v = __float2bfloat16(acc);
  xch[t] = v;
  int idx_t = wi * 96 + hi;
  xcht[((size_t)bb * L_ + idx_t) * DI_ + d] = v;
}

// ---------------- 3: x_dbl proj via MFMA -> scan-order xdblB / xdblC (nt split on z) ----------------
__global__ __launch_bounds__(256, 4) void k_xdbl_mfma(
    const bf16* __restrict__ xch, const bf16* __restrict__ wh,
    float* __restrict__ xdblB, bf16* __restrict__ xdblC) {
  int w = threadIdx.x >> 6, lane = threadIdx.x & 63;
  int bb = blockIdx.y;
  int mtile = blockIdx.x * 4 + w;
  int idx0 = mtile * 16;
  int m = lane & 15, quad = lane >> 4;
  const bf16* arow = xch + ((size_t)bb * L_ + idx0 + m) * 64 + quad * 8;
  short8 a0 = *reinterpret_cast<const short8*>(arow);
  short8 a1 = *reinterpret_cast<const short8*>(arow + 32);
  int ntb = blockIdx.z * 3;
#pragma unroll
  for (int it = 0; it < 3; it++) {
    int nt = ntb + it;
    int n = nt * 16 + m;
    const bf16* brow = wh + n * 64 + quad * 8;
    short8 b0 = *reinterpret_cast<const short8*>(brow);
    short8 b1 = *reinterpret_cast<const short8*>(brow + 32);
    f32x4 acc = {0.f, 0.f, 0.f, 0.f};
    acc = __builtin_amdgcn_mfma_f32_16x16x32_bf16(a0, b0, acc, 0, 0, 0);
    acc = __builtin_amdgcn_mfma_f32_16x16x32_bf16(a1, b1, acc, 0, 0, 0);
    if (n < 136) {
      int k4 = (n >= 102) ? 3 : (n >= 68) ? 2 : (n >= 34) ? 1 : 0;
      int c = n - k4 * 34;
#pragma unroll
      for (int i = 0; i < 4; i++) {
        int r = idx0 + quad * 4 + i;
        int hi2 = r / 96, wi2 = r - hi2 * 96;
        int tr = wi2 * 96 + hi2;
        int ls = (k4 == 0) ? r : (k4 == 1) ? tr : (k4 == 2) ? (L_ - 1 - r) : (L_ - 1 - tr);
        size_t row = (size_t)(bb * K_ + k4) * L_ + ls;
        if (c < 2)       xdblB[row * 12 + 8 + c] = acc[i];
        else if (c < 18) ((bf16*)(xdblB + row * 12))[c - 2] = __float2bfloat16(acc[i]);
        else             xdblC[row * 16 + (c - 18)] = __float2bfloat16(acc[i]);
      }
    }
  }
}

// ---------------- 4: scan1 — per-chunk summaries (h_local, sum dt) ----------------
__global__ __launch_bounds__(256, 4) void k_scan1(
    const float* __restrict__ xdblB, const bf16* __restrict__ xch,
    const bf16* __restrict__ xcht, const float* __restrict__ dtw,
    const float* __restrict__ dtb, const float* __restrict__ aux,
    bf16* __restrict__ hbuf, float* __restrict__ ssum) {
  int w = threadIdx.x >> 6, d = threadIdx.x & 63;
  int chunk = blockIdx.x * 4 + w, k = blockIdx.y, bb = blockIdx.z;
  float w0 = dtw[(k * DI_ + d) * 2 + 0], w1 = dtw[(k * DI_ + d) * 2 + 1];
  float bia = dtb[k * DI_ + d];
  float A1 = aux[k * 64 + d];
  bool chain = (__ballot(aux[256 + k * 64 + d] > 0.5f) == ~0ull);
  float h[N_];
#pragma unroll
  for (int n = 0; n < N_; n++) h[n] = 0.f;
  const float* bB = xdblB + (size_t)(bb * K_ + k) * L_ * 12;
  const bf16* ub = ((k & 1) ? xcht : xch) + (size_t)bb * L_ * DI_;
  int ls0 = chunk * CL_;
  int uidx0 = (k & 2) ? (L_ - 1 - ls0) : ls0;
  int ustep = (k & 2) ? -1 : 1;
  float S = 0.f;
  if (chain) {
#pragma unroll 2
    for (int s = 0; s < CL_; s++) {
      uint4 qb0, qb1; float t0, t1, u;
      ld_bu(bB, ub, d, ls0 + s, uidx0 + s * ustep, qb0, qb1, t0, t1, u);
      float Bv[16];
      unpk(qb0, qb1, Bv);
      float dt = softplusf(fmaf(t0, w0, fmaf(t1, w1, bia)));
      S += dt;
      float du = dt * u;
      float ep[16];
      pow_tree(__expf(dt * A1), ep);
#pragma unroll
      for (int n = 0; n < N_; n++) h[n] = fmaf(ep[n], h[n], du * Bv[n]);
    }
  } else {
    float A[N_];
#pragma unroll
    for (int n = 0; n < N_; n++) A[n] = aux[512 + (k * 64 + d) * N_ + n];
    for (int s = 0; s < CL_; s++) {
      uint4 qb0, qb1; float t0, t1, u;
      ld_bu(bB, ub, d, ls0 + s, uidx0 + s * ustep, qb0, qb1, t0, t1, u);
      float Bv[16];
      unpk(qb0, qb1, Bv);
      float dt = softplusf(fmaf(t0, w0, fmaf(t1, w1, bia)));
      S += dt;
      float du = dt * u;
#pragma unroll
      for (int n = 0; n < N_; n++) h[n] = fmaf(__expf(dt * A[n]), h[n], du * Bv[n]);
    }
  }
  size_t base = (size_t)((bb * K_ + k) * CH_ + chunk) * DI_ + d;
  ssum[base] = S;
#pragma unroll
  for (int n = 0; n < N_; n++) hbuf[base * N_ + n] = __float2bfloat16(h[n]);
}

// ---------------- 5: scan2a — segment-local exclusive scan + raw segment totals ----------------
__global__ __launch_bounds__(256, 4) void k_scan2a(
    const float* __restrict__ aux, const float* __restrict__ ssum,
    bf16* __restrict__ hbuf, float* __restrict__ cumS,
    float* __restrict__ segH, float* __restrict__ segS) {
  int t = blockIdx.x * 256 + threadIdx.x;      // 524288
  int n = t & 15, d = (t >> 4) & 63, kk = (t >> 10) & 3, bb = (t >> 12) & 3, seg = t >> 14;
  float A = aux[512 + (kk * 64 + d) * N_ + n];
  size_t row = (size_t)(bb * K_ + kk) * CH_ * DI_ + d;
  float hp = 0.f, Sc = 0.f;
#pragma unroll 4
  for (int j = 0; j < SEGC; j++) {
    int c = seg * SEGC + j;
    size_t sb = row + (size_t)c * DI_;
    float S = ssum[sb];
    float hl = b2f(hbuf[sb * N_ + n]);
    hbuf[sb * N_ + n] = __float2bfloat16(hp);
    if (n == 0) cumS[sb] = Sc;
    hp = fmaf(__expf(A * S), hp, hl);
    Sc += S;
  }
  size_t sbase = (size_t)(bb * K_ + kk) * SEGN + seg;
  segH[(sbase * DI_ + d) * N_ + n] = hp;
  if (n == 0) segS[sbase * DI_ + d] = Sc;
}

// ---------------- 6: scan2b — serial scan over 32 segments (tiny) ----------------
__global__ void k_scan2b(const float* __restrict__ aux, float* __restrict__ segH,
                         const float* __restrict__ segS) {
  int t = blockIdx.x * 256 + threadIdx.x;  // 16384
  int n = t & 15, d = (t >> 4) & 63, kk = (t >> 10) & 3, bb = t >> 12;
  float A = aux[512 + (kk * 64 + d) * N_ + n];
  float hp = 0.f;
  for (int seg = 0; seg < SEGN; seg++) {
    size_t sbase = (size_t)(bb * K_ + kk) * SEGN + seg;
    size_t si = (sbase * DI_ + d) * N_ + n;
    float H = segH[si];
    float E = __expf(A * segS[sbase * DI_ + d]);
    segH[si] = hp;                          // overwrite with segment-initial state
    hp = fmaf(E, hp, H);
  }
}

// ---------------- 7: scan3 — replay with prefixed segH init, y -> ydir ----------------
__global__ __launch_bounds__(256, 4) void k_scan3(
    const float* __restrict__ xdblB, const bf16* __restrict__ xdblC,
    const bf16* __restrict__ xch, const bf16* __restrict__ xcht,
    const float* __restrict__ dtw, const float* __restrict__ dtb,
    const float* __restrict__ Dsw, const float* __restrict__ aux,
    const bf16* __restrict__ hbuf, const float* __restrict__ cumS,
    const float* __restrict__ segH, bf16* __restrict__ ydir) {
  int w = threadIdx.x >> 6, d = threadIdx.x & 63;
  int chunk = blockIdx.x * 4 + w, k = blockIdx.y, bb = blockIdx.z;
  float w0 = dtw[(k * DI_ + d) * 2 + 0], w1 = dtw[(k * DI_ + d) * 2 + 1];
  float bia = dtb[k * DI_ + d];
  float Dk = Dsw[k * DI_ + d];
  float A1 = aux[k * 64 + d];
  bool chain = (__ballot(aux[256 + k * 64 + d] > 0.5f) == ~0ull);
  float h[N_];
  size_t base = (size_t)((bb * K_ + k) * CH_ + chunk) * DI_ + d;
  int seg = chunk / SEGC;
  size_t sbase = (size_t)(bb * K_ + k) * SEGN + seg;
  float Sc = cumS[base];
  {
    const bf16* hb = hbuf + base * N_;
    uint4 qh0 = *(const uint4*)hb, qh1 = *(const uint4*)(hb + 8);
    unpk(qh0, qh1, h);
    const float* Hin = segH + (sbase * DI_ + d) * N_;
    if (chain) {
      float ep[16];
      pow_tree(__expf(A1 * Sc), ep);
#pragma unroll
      for (int n = 0; n < N_; n++) h[n] = fmaf(ep[n], Hin[n], h[n]);
    } else {
#pragma unroll
      for (int n = 0; n < N_; n++) {
        float A = aux[512 + (k * 64 + d) * N_ + n];
        h[n] = fmaf(__expf(A * Sc), Hin[n], h[n]);
      }
    }
  }
  const float* bB = xdblB + (size_t)(bb * K_ + k) * L_ * 12;
  const bf16* bC = xdblC + (size_t)(bb * K_ + k) * L_ * 16;
  const bf16* ub = ((k & 1) ? xcht : xch) + (size_t)bb * L_ * DI_;
  bf16* yb = ydir + (size_t)(bb * K_ + k) * L_ * DI_;
  int ls0 = chunk * CL_;
  int uidx0 = (k & 2) ? (L_ - 1 - ls0) : ls0;
  int ustep = (k & 2) ? -1 : 1;
  if (chain) {
#pragma unroll 2
    for (int s = 0; s < CL_; s++) {
      uint4 qb0, qb1, qc0, qc1; float t0, t1, u;
      ld_bcu(bB, bC, ub, d, ls0 + s, uidx0 + s * ustep, qb0, qb1, qc0, qc1, t0, t1, u);
      float Bv[16], Cv[16];
      unpk(qb0, qb1, Bv); unpk(qc0, qc1, Cv);
      float dt = softplusf(fmaf(t0, w0, fmaf(t1, w1, bia)));
      float du = dt * u;
      float ep[16];
      pow_tree(__expf(dt * A1), ep);
      float m[16];
#pragma unroll
      for (int n = 0; n < N_; n++) {
        h[n] = fmaf(ep[n], h[n], du * Bv[n]);
        m[n] = h[n] * Cv[n];
      }
      float a0 = m[0] + m[1], a1 = m[2] + m[3], a2 = m[4] + m[5], a3 = m[6] + m[7];
      float a4 = m[8] + m[9], a5 = m[10] + m[11], a6 = m[12] + m[13], a7 = m[14] + m[15];
      float b0 = a0 + a1, b1 = a2 + a3, b2 = a4 + a5, b3 = a6 + a7;
      float y = fmaf(Dk, u, (b0 + b1) + (b2 + b3));
      yb[(size_t)(ls0 + s) * DI_ + d] = __float2bfloat16(y);
    }
  } else {
    float A[N_];
#pragma unroll
    for (int n = 0; n < N_; n++) A[n] = aux[512 + (k * 64 + d) * N_ + n];
    for (int s = 0; s < CL_; s++) {
      uint4 qb0, qb1, qc0, qc1; float t0, t1, u;
      ld_bcu(bB, bC, ub, d, ls0 + s, uidx0 + s * ustep, qb0, qb1, qc0, qc1, t0, t1, u);
      float Bv[16], Cv[16];
      unpk(qb0, qb1, Bv); unpk(qc0, qc1, Cv);
      float dt = softplusf(fmaf(t0, w0, fmaf(t1, w1, bia)));
      float du = dt * u;
      float y = 0.f;
#pragma unroll
      for (int n = 0; n < N_; n++) {
        h[n] = fmaf(__expf(dt * A[n]), h[n], du * Bv[n]);
        y = fmaf(h[n], Cv[n], y);
      }
      y = fmaf(Dk, u, y);
      yb[(size_t)(ls0 + s) * DI_ + d] = __float2bfloat16(y);
    }
  }
}

// ---------------- 8: sum 4 dirs, LN(64)*silu(z), out_proj, residual -> xm ----------------
__global__ void k_combine(const bf16* __restrict__ ydir, const bf16* __restrict__ xzBh,
                          const float* __restrict__ xd, const float* __restrict__ onw,
                          const float* __restrict__ onb, const float* __restrict__ outw,
                          const float* __restrict__ mssc, float* __restrict__ xm) {
  int w = threadIdx.x >> 6, d = threadIdx.x & 63;
  int idx = blockIdx.x * 4 + w, bb = blockIdx.y;
  int b = bb & 1, co = (bb >> 1) * HD_;
  int hii = idx / 96, wii = idx - hii * 96;
  int lt = wii * 96 + hii;
  const bf16* yd = ydir + (size_t)bb * K_ * L_ * DI_;
  float y = b2f(yd[((size_t)0 * L_ + idx) * DI_ + d])
          + b2f(yd[((size_t)1 * L_ + lt) * DI_ + d])
          + b2f(yd[((size_t)2 * L_ + (L_ - 1 - idx)) * DI_ + d])
          + b2f(yd[((size_t)3 * L_ + (L_ - 1 - lt)) * DI_ + d]);
  float s = y, sq = y * y;
#pragma unroll
  for (int m = 1; m < 64; m <<= 1) { s += __shfl_xor(s, m, 64); sq += __shfl_xor(sq, m, 64); }
  float mean = s * (1.f / DI_);
  float var = sq * (1.f / DI_) - mean * mean;
  float rstd = rsqrtf(var + EPSF);
  float yn = (y - mean) * rstd * onw[d] + onb[d];
  float z = b2f(xzBh[(size_t)(bb * L_ + idx) * 64 + d]);
  float g = yn * (z / (1.f + __expf(-z)));
  __shared__ float gs[4][DI_];
  gs[w][d] = g;
  __syncthreads();
  if (d < HD_) {
    float acc = 0.f;
#pragma unroll
    for (int dd = 0; dd < DI_; dd++) acc = fmaf(gs[w][dd], outw[dd * HD_ + d], acc);
    size_t xi = (size_t)(b * C_ + co + d) * L_ + idx;
    float xp = xd[xi];
    xm[xi] = mssc[0] * xp + xp + acc;
  }
}

// ---------------- 9: fused instance-norm stats (xm) + global mean/max pool (x) ----------------
__global__ __launch_bounds__(1024) void k_stats(
    const float* __restrict__ xm, const float* __restrict__ x,
    float* __restrict__ inm, float* __restrict__ inr,
    float* __restrict__ xmean, float* __restrict__ xmax) {
  int bc = blockIdx.x, t = threadIdx.x;
  const float* pm = xm + (size_t)bc * L_;
  const float* px = x + (size_t)bc * L_;
  float s = 0.f, sq = 0.f, xs = 0.f, mx = -1e30f;
  for (int i = t; i < L_; i += 1024) {
    float v = pm[i]; s += v; sq = fmaf(v, v, sq);
    float xv = px[i]; xs += xv; mx = fmaxf(mx, xv);
  }
  __shared__ float red[64];
#pragma unroll
  for (int m = 1; m < 64; m <<= 1) {
    s += __shfl_xor(s, m, 64); sq += __shfl_xor(sq, m, 64);
    xs += __shfl_xor(xs, m, 64); mx = fmaxf(mx, __shfl_xor(mx, m, 64));
  }
  int wid = t >> 6;
  if ((t & 63) == 0) { red[wid] = s; red[16 + wid] = sq; red[32 + wid] = xs; red[48 + wid] = mx; }
  __syncthreads();
  if (t == 0) {
    s = 0.f; sq = 0.f; xs = 0.f; mx = -1e30f;
#pragma unroll
    for (int i = 0; i < 16; i++) {
      s += red[i]; sq += red[16 + i]; xs += red[32 + i]; mx = fmaxf(mx, red[48 + i]);
    }
    float mean = s * (1.f / L_);
    float var = sq * (1.f / L_) - mean * mean;
    inm[bc] = mean;
    inr[bc] = rsqrtf(var + EPSF);
    xmean[bc] = xs * (1.f / L_);
    xmax[bc] = mx;
  }
}

// ---------------- 10: fused IN+leaky+gate (per tap) + axial convs + BN + relu -> skip ----------------
__global__ void k_axbn(const float* __restrict__ xm, const float* __restrict__ x,
                       const float* __restrict__ inm, const float* __restrict__ inr,
                       const float* __restrict__ msw, const float* __restrict__ msb,
                       const float* __restrict__ xmean, const float* __restrict__ xmax,
                       const float* __restrict__ maw, const float* __restrict__ mab,
                       const float* __restrict__ hw, const float* __restrict__ hb,
                       const float* __restrict__ wwt, const float* __restrict__ wb,
                       const float* __restrict__ bnw, const float* __restrict__ bnb,
                       const float* __restrict__ bnm, const float* __restrict__ bnv,
                       float* __restrict__ skipo) {
  int t = blockIdx.x * 256 + threadIdx.x;
  int bc = t / L_, c = bc & 63, b = bc >> 6;   // uniform per block (256 | L)
  __shared__ float gsh;
  if (threadIdx.x < 64) {
    int ic = threadIdx.x;
    float p = xmean[b * 64 + ic] * maw[(c * 128 + ic) * 9 + 4]
            + xmax[b * 64 + ic] * maw[(c * 128 + 64 + ic) * 9 + 4];
#pragma unroll
    for (int m = 1; m < 64; m <<= 1) p += __shfl_xor(p, m, 64);
    if (ic == 0) gsh = 1.f / (1.f + __expf(-(p + mab[c])));
  }
  __syncthreads();
  float gate = gsh, im = inm[bc], ir = inr[bc], mw = msw[c], mb = msb[c];
  int wi = t % W_, hi = (t / W_) % H_;
  auto xsv = [&](int tt) -> float {
    float v = xm[tt];
    v = (v - im) * ir * mw + mb;
    v = v > 0.f ? v : 0.01f * v;
    return v + gate * x[tt];
  };
  float a = xsv(t);
  float hacc = hb[c];
#pragma unroll
  for (int dy = -1; dy <= 1; dy++) {
    int hh = hi + dy; if (hh < 0 || hh >= H_) continue;
    hacc = fmaf(xsv(t + dy * W_), hw[c * 3 + dy + 1], hacc);
  }
  float wacc = wb[c];
#pragma unroll
  for (int dx = -1; dx <= 1; dx++) {
    int ww = wi + dx; if (ww < 0 || ww >= W_) continue;
    wacc = fmaf(xsv(t + dx), wwt[c * 3 + dx + 1], wacc);
  }
  float v = a + hacc + wacc;
  float sv = (v - bnm[c]) * rsqrtf(bnv[c] + EPSF) * bnw[c] + bnb[c];
  skipo[t] = fmaxf(sv, 0.f);
}

// ---------------- 11: 1x1 conv (64->128) + 2x2 maxpool -> down (oc split over z) ----------------
__global__ void k_pwpool(const float* __restrict__ skipo, const float* __restrict__ pww,
                         const float* __restrict__ pwb, float* __restrict__ down) {
  int h2 = blockIdx.x, b = blockIdx.y, t = threadIdx.x;
  int oc0 = blockIdx.z * 32;
  __shared__ float sk[64 * 192];  // [c][r(2)][w(96)]
  for (int i = t; i < 64 * 192; i += 256) {
    int c = i / 192, rw = i % 192, r = rw / 96, wcol = rw % 96;
    sk[i] = skipo[((size_t)(b * C_ + c) * H_ + (2 * h2 + r)) * W_ + wcol];
  }
  __syncthreads();
  for (int o = t; o < 32 * 48; o += 256) {
    int oc = oc0 + o / 48, w2 = o % 48;
    float s0 = 0.f, s1 = 0.f, s2 = 0.f, s3 = 0.f;
#pragma unroll 8
    for (int c = 0; c < 64; c++) {
      float wv = pww[oc * 64 + c];
      const float* sp = &sk[c * 192 + 2 * w2];
      s0 = fmaf(sp[0], wv, s0);
      s1 = fmaf(sp[1], wv, s1);
      s2 = fmaf(sp[96], wv, s2);
      s3 = fmaf(sp[97], wv, s3);
    }
    float v = fmaxf(fmaxf(s0, s1), fmaxf(s2, s3)) + pwb[oc];
    down[((size_t)(b * OC_ + oc) * 48 + h2) * 48 + w2] = v;
  }
}

extern "C" void kernel_launch(void* const* d_in, const int* in_sizes, int n_in,
                              void* d_out, int out_size, void* d_ws, size_t ws_size,
                              hipStream_t stream) {
  const float* x     = (const float*)d_in[0];
  const float* dw33w = (const float*)d_in[1];
  const float* dw33b = (const float*)d_in[2];
  const float* msw   = (const float*)d_in[3];
  const float* msb   = (const float*)d_in[4];
  const float* mssc  = (const float*)d_in[5];
  const float* lnw   = (const float*)d_in[6];
  const float* lnb   = (const float*)d_in[7];
  const float* inw   = (const float*)d_in[8];
  const float* cw    = (const float*)d_in[9];
  const float* cb    = (const float*)d_in[10];
  const float* xpw   = (const float*)d_in[11];
  const float* dtw   = (const float*)d_in[12];
  const float* dtb   = (const float*)d_in[13];
  const float* alog  = (const float*)d_in[14];
  const float* Dsw   = (const float*)d_in[15];
  const float* onw   = (const float*)d_in[16];
  const float* onb   = (const float*)d_in[17];
  const float* outw  = (const float*)d_in[18];
  const float* maw   = (const float*)d_in[19];
  const float* mab   = (const float*)d_in[20];
  const float* ahw   = (const float*)d_in[21];
  const float* ahb   = (const float*)d_in[22];
  const float* aww   = (const float*)d_in[23];
  const float* awb   = (const float*)d_in[24];
  const float* pww   = (const float*)d_in[25];
  const float* pwb   = (const float*)d_in[26];
  const float* bnw   = (const float*)d_in[27];
  const float* bnb   = (const float*)d_in[28];
  const float* bnm   = (const float*)d_in[29];
  const float* bnv   = (const float*)d_in[30];

  float* ws = (float*)d_ws;
  float* xd    = ws;                           // 1,179,648
  float* hreg  = xd + 1179648;                 // 12,582,912 slots: hbuf bf16 (25.2M)
  bf16*  hbuf  = (bf16*)hreg;
  bf16*  xzAh  = (bf16*)hreg;                  // overlay: xp bf16, dead before scan1
  bf16*  xzBh  = (bf16*)(hreg + 12582912);     // 1,179,648 slots
  float* xdblB = hreg + 12582912 + 1179648;    // 1,769,472
  bf16*  xdblC = (bf16*)(xdblB + 1769472);     // 1,179,648 slots
  float* ssum  = xdblB + 1769472 + 1179648;    // 1,572,864
  bf16*  ydir  = (bf16*)(ssum + 1572864);      // 4,718,592 slots
  float* xmR   = ssum + 1572864 + 4718592;     // 1,179,648 (xch early, xm later)
  bf16*  xch   = (bf16*)xmR;
  float* xm    = xmR;
  float* st    = xmR + 1179648;                // 512
  float* inm = st, *inr = st + 128, *xmean = st + 256, *xmaxv = st + 384;
  float* aux   = st + 512;                     // 4,608
  bf16*  wh    = (bf16*)(aux + 4608);          // 4,608 slots
  float* cumS  = aux + 4608 + 4608;            // 1,572,864
  float* segH  = cumS + 1572864;               // 524,288
  float* segS  = segH + 524288;                // 32,768
  bf16*  xcht  = (bf16*)(segS + 32768);        // 1,179,648 slots

  float* outp = (float*)d_out;
  float* down = outp;
  float* skipo = outp + DOWN_SZ;

  dim3 b256(256);
  int nEl = B_ * C_ * L_;

  k_front<<<dim3(L_ / 32, BB_), b256, 0, stream>>>(x, dw33w, dw33b, lnw, lnb, inw,
                                                   xpw, alog, xd, xzAh, xzBh, wh, aux);
  k_dwsilu<<<dim3(BB_ * L_ * DI_ / 256), b256, 0, stream>>>(xzAh, cw, cb, xch, xcht);
  k_xdbl_mfma<<<dim3(L_ / 64, BB_, 3), b256, 0, stream>>>(xch, wh, xdblB, xdblC);
  k_scan1<<<dim3(CH_ / 4, K_, BB_), b256, 0, stream>>>(xdblB, xch, xcht, dtw, dtb, aux, hbuf, ssum);
  k_scan2a<<<dim3(BB_ * K_ * SEGN * DI_ * N_ / 256), b256, 0, stream>>>(aux, ssum, hbuf, cumS, segH, segS);
  k_scan2b<<<dim3(BB_ * K_ * DI_ * N_ / 256), b256, 0, stream>>>(aux, segH, segS);
  k_scan3<<<dim3(CH_ / 4, K_, BB_), b256, 0, stream>>>(xdblB, xdblC, xch, xcht, dtw, dtb, Dsw,
                                                      aux, hbuf, cumS, segH, ydir);
  k_combine<<<dim3(L_ / 4, BB_), b256, 0, stream>>>(ydir, xzBh, xd, onw, onb, outw, mssc, xm);
  k_stats<<<dim3(B_ * C_), dim3(1024), 0, stream>>>(xm, x, inm, inr, xmean, xmaxv);
  k_axbn<<<dim3((nEl + 255) / 256), b256, 0, stream>>>(xm, x, inm, inr, msw, msb, xmean, xmaxv,
                                                      maw, mab, ahw, ahb, aww, awb,
                                                      bnw, bnb, bnm, bnv, skipo);
  k_pwpool<<<dim3(48, B_, 4), b256, 0, stream>>>(skipo, pww, pwb, down);
}